// Round 2
// baseline (705.693 us; speedup 1.0000x reference)
//
#include <hip/hip_runtime.h>
#include <math.h>

#define N_NODES 100000
#define N_EDGES 1000000
#define F_IN 64
#define HID 128
#define C2 256            // 2*HID (both BN variants side by side)
#define NPART 512         // zstats partial-sum blocks
#define GN 32             // nodes per block-iteration in ynode_kernel

// ---------------------------------------------------------------- counts
__global__ __launch_bounds__(256) void count_kernel(const int* __restrict__ ei,
                                                    int* __restrict__ c0,
                                                    int* __restrict__ c1) {
  int stride = gridDim.x * blockDim.x;
  for (int e = blockIdx.x * blockDim.x + threadIdx.x; e < N_EDGES; e += stride) {
    atomicAdd(&c0[ei[e]], 1);
    atomicAdd(&c1[ei[N_EDGES + e]], 1);
  }
}

// ------------------------------------------- weighted BN statistics (partials)
// z = relu(x @ W1 + b1); accumulate c0*z, c0*z^2, c1*z, c1*z^2 per feature.
__global__ __launch_bounds__(128) void zstats_kernel(const float* __restrict__ x,
                                                     const float* __restrict__ W1,
                                                     const float* __restrict__ b1,
                                                     const int* __restrict__ c0,
                                                     const int* __restrict__ c1,
                                                     float* __restrict__ Spart) {
  __shared__ float w1s[F_IN * HID];
  __shared__ float xs[F_IN];
  int f = threadIdx.x;  // 0..127
  for (int i = f; i < F_IN * HID; i += 128) w1s[i] = W1[i];
  float b = b1[f];
  float a10 = 0.f, a20 = 0.f, a11 = 0.f, a21 = 0.f;
  for (int n = blockIdx.x; n < N_NODES; n += gridDim.x) {
    __syncthreads();
    if (f < F_IN) xs[f] = x[(size_t)n * F_IN + f];
    __syncthreads();
    float z = b;
#pragma unroll
    for (int k = 0; k < F_IN; ++k) z = fmaf(xs[k], w1s[k * HID + f], z);
    z = fmaxf(z, 0.f);
    float cc0 = (float)c0[n], cc1 = (float)c1[n];
    a10 = fmaf(cc0, z, a10);
    a20 = fmaf(cc0, z * z, a20);
    a11 = fmaf(cc1, z, a11);
    a21 = fmaf(cc1, z * z, a21);
  }
  float* Sp = Spart + (size_t)blockIdx.x * 512;
  Sp[f] = a10;
  Sp[128 + f] = a20;
  Sp[256 + f] = a11;
  Sp[384 + f] = a21;
}

// ---------------------------------- reduce partials -> scale/shift per side
// P layout: [0:128)=scale0, [128:256)=shift0, [256:384)=scale1, [384:512)=shift1
__global__ __launch_bounds__(512) void finalize_kernel(const float* __restrict__ Spart,
                                                       const float* __restrict__ gamma,
                                                       const float* __restrict__ beta,
                                                       float* __restrict__ P) {
  __shared__ float S[512];
  int t = threadIdx.x;
  float s = 0.f;
#pragma unroll 8
  for (int bgroup = 0; bgroup < NPART; ++bgroup) s += Spart[(size_t)bgroup * 512 + t];
  S[t] = s;
  __syncthreads();
  if (t < 128) {
    const float invE = 1.0f / (float)N_EDGES;
    int f = t;
    float mu0 = S[f] * invE;
    float v0 = fmaxf(S[128 + f] * invE - mu0 * mu0, 0.f);
    float sc0 = gamma[f] * rsqrtf(v0 + 1e-5f);
    P[f] = sc0;
    P[128 + f] = beta[f] - mu0 * sc0;
    float mu1 = S[256 + f] * invE;
    float v1 = fmaxf(S[384 + f] * invE - mu1 * mu1, 0.f);
    float sc1 = gamma[f] * rsqrtf(v1 + 1e-5f);
    P[256 + f] = sc1;
    P[384 + f] = beta[f] - mu1 * sc1;
  }
}

// -------------------- build Wc (128x256, scaled W2 both sides) and q (256)
__global__ __launch_bounds__(256) void prep_kernel(const float* __restrict__ W2,
                                                   const float* __restrict__ b2,
                                                   const float* __restrict__ P,
                                                   float* __restrict__ Wc,
                                                   float* __restrict__ q) {
  int j = threadIdx.x;          // 0..255
  int side = j >> 7, c = j & 127;
  if (blockIdx.x < HID) {
    int f = blockIdx.x;
    Wc[f * C2 + j] = P[side * 256 + f] * W2[f * HID + c];
  } else {
    float acc = b2[c];
    for (int f = 0; f < HID; ++f) acc = fmaf(P[side * 256 + 128 + f], W2[f * HID + c], acc);
    q[j] = acc;
  }
}

// -------------------------------------------- per-node Y = Z @ Wc + q, norms
__device__ __forceinline__ void fma4(float4& a, float s, const float4& v) {
  a.x = fmaf(s, v.x, a.x);
  a.y = fmaf(s, v.y, a.y);
  a.z = fmaf(s, v.z, a.z);
  a.w = fmaf(s, v.w, a.w);
}

__global__ __launch_bounds__(512) void ynode_kernel(const float* __restrict__ x,
                                                    const float* __restrict__ W1,
                                                    const float* __restrict__ b1,
                                                    const float* __restrict__ Wc,
                                                    const float* __restrict__ q,
                                                    float* __restrict__ Y,
                                                    float* __restrict__ n1o,
                                                    float* __restrict__ n2o) {
  __shared__ float wcs[HID * C2];   // 128 KB
  __shared__ float zs[GN][HID];     // 16 KB
  __shared__ float xs[GN][F_IN];    // 8 KB
  int tid = threadIdx.x;
  for (int i = tid; i < HID * C2; i += 512) wcs[i] = Wc[i];

  int lane = tid & 63;
  int wav = tid >> 6;       // 0..7  -> node group
  int col0 = lane * 4;      // 0..252: columns of the 256-wide output
  float4 qv = *(const float4*)&q[col0];

  int f = tid & 127;        // z-phase feature
  int zn = tid >> 7;        // 0..3
  float bb = b1[f];

  const int ntiles = N_NODES / GN;  // 3125 exactly (100000 = 32*3125)
  for (int t = blockIdx.x; t < ntiles; t += gridDim.x) {
    int nbase = t * GN;
    __syncthreads();  // previous iteration fully done with xs/zs
    for (int i = tid; i < GN * F_IN; i += 512) {
      int n = i >> 6, k = i & 63;
      xs[n][k] = x[(size_t)(nbase + n) * F_IN + k];
    }
    __syncthreads();
    // z phase: thread covers feature f for nodes zn, zn+4, ...
#pragma unroll
    for (int nn = zn; nn < GN; nn += 4) {
      float z = bb;
#pragma unroll
      for (int k = 0; k < F_IN; ++k) z = fmaf(xs[nn][k], W1[k * HID + f], z);
      zs[nn][f] = fmaxf(z, 0.f);
    }
    __syncthreads();
    // GEMM phase: wave `wav` computes nodes nbase+4*wav .. +3, all 256 cols
    int nb = 4 * wav;
    float4 acc0 = qv, acc1 = qv, acc2 = qv, acc3 = qv;
    for (int k = 0; k < HID; k += 4) {
      float4 z0 = *(const float4*)&zs[nb + 0][k];
      float4 z1 = *(const float4*)&zs[nb + 1][k];
      float4 z2 = *(const float4*)&zs[nb + 2][k];
      float4 z3 = *(const float4*)&zs[nb + 3][k];
      float4 w0 = *(const float4*)&wcs[(k + 0) * C2 + col0];
      float4 w1v = *(const float4*)&wcs[(k + 1) * C2 + col0];
      float4 w2v = *(const float4*)&wcs[(k + 2) * C2 + col0];
      float4 w3v = *(const float4*)&wcs[(k + 3) * C2 + col0];
      fma4(acc0, z0.x, w0); fma4(acc0, z0.y, w1v); fma4(acc0, z0.z, w2v); fma4(acc0, z0.w, w3v);
      fma4(acc1, z1.x, w0); fma4(acc1, z1.y, w1v); fma4(acc1, z1.z, w2v); fma4(acc1, z1.w, w3v);
      fma4(acc2, z2.x, w0); fma4(acc2, z2.y, w1v); fma4(acc2, z2.z, w2v); fma4(acc2, z2.w, w3v);
      fma4(acc3, z3.x, w0); fma4(acc3, z3.y, w1v); fma4(acc3, z3.z, w2v); fma4(acc3, z3.w, w3v);
    }
    // norms: lanes 0..31 hold side-0 cols (0..127), lanes 32..63 side-1
    float s0 = acc0.x * acc0.x + acc0.y * acc0.y + acc0.z * acc0.z + acc0.w * acc0.w;
    float s1 = acc1.x * acc1.x + acc1.y * acc1.y + acc1.z * acc1.z + acc1.w * acc1.w;
    float s2 = acc2.x * acc2.x + acc2.y * acc2.y + acc2.z * acc2.z + acc2.w * acc2.w;
    float s3 = acc3.x * acc3.x + acc3.y * acc3.y + acc3.z * acc3.z + acc3.w * acc3.w;
#pragma unroll
    for (int m = 1; m <= 16; m <<= 1) {
      s0 += __shfl_xor(s0, m);
      s1 += __shfl_xor(s1, m);
      s2 += __shfl_xor(s2, m);
      s3 += __shfl_xor(s3, m);
    }
    size_t nrow = (size_t)(nbase + nb);
    *(float4*)&Y[(nrow + 0) * C2 + col0] = acc0;
    *(float4*)&Y[(nrow + 1) * C2 + col0] = acc1;
    *(float4*)&Y[(nrow + 2) * C2 + col0] = acc2;
    *(float4*)&Y[(nrow + 3) * C2 + col0] = acc3;
    if (lane == 0) {
      n1o[nrow + 0] = sqrtf(s0);
      n1o[nrow + 1] = sqrtf(s1);
      n1o[nrow + 2] = sqrtf(s2);
      n1o[nrow + 3] = sqrtf(s3);
    } else if (lane == 32) {
      n2o[nrow + 0] = sqrtf(s0);
      n2o[nrow + 1] = sqrtf(s1);
      n2o[nrow + 2] = sqrtf(s2);
      n2o[nrow + 3] = sqrtf(s3);
    }
  }
}

// ---------------------------------------------------------- per-edge cosine
__global__ __launch_bounds__(256) void edge_kernel(const int* __restrict__ ei,
                                                   const float* __restrict__ Y,
                                                   const float* __restrict__ n1,
                                                   const float* __restrict__ n2,
                                                   float* __restrict__ out) {
  int tid = blockIdx.x * blockDim.x + threadIdx.x;
  int g = tid >> 4;  // 16 lanes per edge
  int l = tid & 15;
  int ngroups = (gridDim.x * blockDim.x) >> 4;
  for (int e = g; e < N_EDGES; e += ngroups) {
    int i = ei[e], j = ei[N_EDGES + e];
    const float4* a = (const float4*)&Y[(size_t)i * C2 + l * 8];
    const float4* b = (const float4*)&Y[(size_t)j * C2 + 128 + l * 8];
    float4 a0 = a[0], a1 = a[1];
    float4 b0 = b[0], b1 = b[1];
    float d = a0.x * b0.x + a0.y * b0.y + a0.z * b0.z + a0.w * b0.w +
              a1.x * b1.x + a1.y * b1.y + a1.z * b1.z + a1.w * b1.w;
    d += __shfl_xor(d, 8);
    d += __shfl_xor(d, 4);
    d += __shfl_xor(d, 2);
    d += __shfl_xor(d, 1);
    if (l == 0) {
      float nn = n1[i] * n2[j];
      float cosv = d / fmaxf(nn, 1e-8f);
      out[e] = (cosv + 1.0f) * 0.5f;
    }
  }
}

// ------------------------------------------------------------------ launch
extern "C" void kernel_launch(void* const* d_in, const int* in_sizes, int n_in,
                              void* d_out, int out_size, void* d_ws, size_t ws_size,
                              hipStream_t stream) {
  const float* x = (const float*)d_in[0];
  const int* ei = (const int*)d_in[1];
  const float* W1 = (const float*)d_in[2];
  const float* b1 = (const float*)d_in[3];
  const float* gamma = (const float*)d_in[4];
  const float* beta = (const float*)d_in[5];
  const float* W2 = (const float*)d_in[6];
  const float* b2 = (const float*)d_in[7];
  float* out = (float*)d_out;

  auto align = [](size_t v) { return (v + 255) & ~(size_t)255; };
  char* ws = (char*)d_ws;
  size_t o_c0 = 0;
  size_t o_c1 = o_c0 + align(N_NODES * sizeof(int));
  size_t o_cend = o_c1 + align(N_NODES * sizeof(int));
  size_t o_sp = o_cend;
  size_t o_P = o_sp + align((size_t)NPART * 512 * sizeof(float));
  size_t o_wc = o_P + align(512 * sizeof(float));
  size_t o_q = o_wc + align((size_t)HID * C2 * sizeof(float));
  size_t o_n1 = o_q + align(C2 * sizeof(float));
  size_t o_n2 = o_n1 + align(N_NODES * sizeof(float));
  size_t o_Y = o_n2 + align(N_NODES * sizeof(float));

  int* c0 = (int*)(ws + o_c0);
  int* c1 = (int*)(ws + o_c1);
  float* Sp = (float*)(ws + o_sp);
  float* P = (float*)(ws + o_P);
  float* Wc = (float*)(ws + o_wc);
  float* q = (float*)(ws + o_q);
  float* n1 = (float*)(ws + o_n1);
  float* n2 = (float*)(ws + o_n2);
  float* Y = (float*)(ws + o_Y);

  hipMemsetAsync(ws + o_c0, 0, o_cend, stream);
  count_kernel<<<2048, 256, 0, stream>>>(ei, c0, c1);
  zstats_kernel<<<NPART, 128, 0, stream>>>(x, W1, b1, c0, c1, Sp);
  finalize_kernel<<<1, 512, 0, stream>>>(Sp, gamma, beta, P);
  prep_kernel<<<HID + 1, 256, 0, stream>>>(W2, b2, P, Wc, q);
  ynode_kernel<<<256, 512, 0, stream>>>(x, W1, b1, Wc, q, Y, n1, n2);
  edge_kernel<<<2048, 256, 0, stream>>>(ei, Y, n1, n2, out);
}

// Round 4
// 314.985 us; speedup vs baseline: 2.2404x; 2.2404x over previous
//
#include <hip/hip_runtime.h>
#include <math.h>

#define N_NODES 100000
#define N_EDGES 1000000
#define F_IN 64
#define HID 128
#define C2 256
#define GN 32
#define ZBLOCKS 1024   // zpass grid / number of stat partials
#define FB 64          // finalize_a blocks

typedef unsigned int uint32;

// ---- bf16 helpers (RNE) ----
__device__ __forceinline__ float bf_round(float f) {
  union { float f; uint32 u; } c; c.f = f;
  c.u = (c.u + 0x7fffu + ((c.u >> 16) & 1u)) & 0xffff0000u;
  return c.f;
}
__device__ __forceinline__ unsigned short bf_top(float f) {
  union { float f; uint32 u; } c; c.f = f;
  return (unsigned short)(c.u >> 16);
}
__device__ __forceinline__ float bf_lo(uint32 u) {
  union { uint32 u; float f; } c; c.u = u << 16; return c.f;
}
__device__ __forceinline__ float bf_hi(uint32 u) {
  union { uint32 u; float f; } c; c.u = u & 0xffff0000u; return c.f;
}

__device__ __forceinline__ void fma4(float4& a, float s, const float4& v) {
  a.x = fmaf(s, v.x, a.x);
  a.y = fmaf(s, v.y, a.y);
  a.z = fmaf(s, v.z, a.z);
  a.w = fmaf(s, v.w, a.w);
}

// ---------------------------------------------------------------- counts
__global__ __launch_bounds__(256) void count_kernel(const int* __restrict__ ei,
                                                    int* __restrict__ c0,
                                                    int* __restrict__ c1) {
  int stride = gridDim.x * blockDim.x;
  for (int e = blockIdx.x * blockDim.x + threadIdx.x; e < N_EDGES; e += stride) {
    atomicAdd(&c0[ei[e]], 1);
    atomicAdd(&c1[ei[N_EDGES + e]], 1);
  }
}

// ------------------------------- Z = relu(x@W1+b1) + weighted stat partials
__global__ __launch_bounds__(256, 4) void zpass_kernel(const float* __restrict__ x,
                                                       const float* __restrict__ W1,
                                                       const float* __restrict__ b1,
                                                       const int* __restrict__ c0,
                                                       const int* __restrict__ c1,
                                                       float* __restrict__ Z,
                                                       float* __restrict__ Spart) {
  __shared__ float xs[GN * F_IN];  // 8 KB; reused as 4x256 partial buffer at end
  int tid = threadIdx.x;
  int f = tid & 127, h = tid >> 7;
  float wv[F_IN];
#pragma unroll
  for (int k = 0; k < F_IN; ++k) wv[k] = W1[k * HID + f];
  float bb = b1[f];
  float a10 = 0.f, a20 = 0.f, a11 = 0.f, a21 = 0.f;
  float4* xs4 = (float4*)xs;
  const int ntiles = N_NODES / GN;  // 3125
  for (int t = blockIdx.x; t < ntiles; t += ZBLOCKS) {
    int nbase = t * GN;
    __syncthreads();
    const float4* xg = (const float4*)(x + (size_t)nbase * F_IN);
    xs4[tid] = xg[tid];
    xs4[tid + 256] = xg[tid + 256];
    __syncthreads();
#pragma unroll
    for (int nn = h; nn < GN; nn += 2) {
      const float4* xv = (const float4*)(xs + nn * F_IN);
      float z = bb;
#pragma unroll
      for (int kq = 0; kq < F_IN / 4; ++kq) {
        float4 xq = xv[kq];
        z = fmaf(xq.x, wv[4 * kq + 0], z);
        z = fmaf(xq.y, wv[4 * kq + 1], z);
        z = fmaf(xq.z, wv[4 * kq + 2], z);
        z = fmaf(xq.w, wv[4 * kq + 3], z);
      }
      z = fmaxf(z, 0.f);
      int gn = nbase + nn;
      Z[(size_t)gn * HID + f] = z;
      float cc0 = (float)c0[gn], cc1 = (float)c1[gn];
      float z2 = z * z;
      a10 = fmaf(cc0, z, a10);
      a20 = fmaf(cc0, z2, a20);
      a11 = fmaf(cc1, z, a11);
      a21 = fmaf(cc1, z2, a21);
    }
  }
  __syncthreads();
  xs[0 * 256 + h * 128 + f] = a10;
  xs[1 * 256 + h * 128 + f] = a20;
  xs[2 * 256 + h * 128 + f] = a11;
  xs[3 * 256 + h * 128 + f] = a21;
  __syncthreads();
  for (int i = tid; i < 512; i += 256) {
    int st = i >> 7, ff = i & 127;
    Spart[(size_t)blockIdx.x * 512 + i] = xs[st * 256 + ff] + xs[st * 256 + 128 + ff];
  }
}

// ------------------------------------- two-stage deterministic stat reduce
__global__ __launch_bounds__(512) void finalize_a(const float* __restrict__ Spart,
                                                  float* __restrict__ S2) {
  int t = threadIdx.x, b = blockIdx.x;
  float s = 0.f;
  for (int p = b; p < ZBLOCKS; p += FB) s += Spart[(size_t)p * 512 + t];
  S2[(size_t)b * 512 + t] = s;
}

// P[0:128)=scale0, P[256:384)=scale1 ; q[256] = shift@W2 + b2 (both sides)
__global__ __launch_bounds__(512) void finalize_b(const float* __restrict__ S2,
                                                  const float* __restrict__ gamma,
                                                  const float* __restrict__ beta,
                                                  const float* __restrict__ W2,
                                                  const float* __restrict__ b2,
                                                  float* __restrict__ P,
                                                  float* __restrict__ q) {
  __shared__ float S[512];
  __shared__ float sh[256];
  int t = threadIdx.x;
  float s = 0.f;
  for (int b = 0; b < FB; ++b) s += S2[(size_t)b * 512 + t];
  S[t] = s;
  __syncthreads();
  if (t < 128) {
    const float invE = 1.0f / (float)N_EDGES;
    float mu0 = S[t] * invE;
    float v0 = fmaxf(S[128 + t] * invE - mu0 * mu0, 0.f);
    float sc0 = gamma[t] * rsqrtf(v0 + 1e-5f);
    P[t] = sc0;
    sh[t] = beta[t] - mu0 * sc0;
    float mu1 = S[256 + t] * invE;
    float v1 = fmaxf(S[384 + t] * invE - mu1 * mu1, 0.f);
    float sc1 = gamma[t] * rsqrtf(v1 + 1e-5f);
    P[256 + t] = sc1;
    sh[128 + t] = beta[t] - mu1 * sc1;
  }
  __syncthreads();
  if (t < 256) {
    int side = t >> 7, c = t & 127;
    float acc = b2[c];
    for (int ff = 0; ff < HID; ++ff) acc = fmaf(sh[side * 128 + ff], W2[ff * HID + c], acc);
    q[t] = acc;
  }
}

// ---------------- Y(bf16) = Z @ (scale_s ⊙ W2) + q_s, per-side blocks, norms
__global__ __launch_bounds__(512, 4) void ygemm_kernel(const float* __restrict__ Z,
                                                       const float* __restrict__ W2,
                                                       const float* __restrict__ P,
                                                       const float* __restrict__ q,
                                                       unsigned short* __restrict__ Yb,
                                                       float* __restrict__ n1o,
                                                       float* __restrict__ n2o) {
  __shared__ float wcs[HID * HID];  // 64 KB
  __shared__ float zs[GN * HID];    // 16 KB
  int tid = threadIdx.x;
  int sd = blockIdx.x & 1;
  const float4* w24 = (const float4*)W2;
  float4* wcs4w = (float4*)wcs;
  for (int i = tid; i < HID * HID / 4; i += 512) {
    int k = i >> 5;
    float4 w = w24[i];
    float sc = P[sd * 256 + k];
    w.x *= sc; w.y *= sc; w.z *= sc; w.w *= sc;
    wcs4w[i] = w;
  }
  int lane = tid & 63;
  int wvi = tid >> 6;       // wave 0..7
  int nb = wvi * 4;         // node offset in tile
  int ch = (lane & 31) * 4; // col in 128-wide half
  int k0 = (lane >> 5) * 64;
  // BUGFIX (R3): only the k0==0 half seeds the bias; the shfl_xor(32) merge
  // sums both halves, so seeding both would add q twice.
  float4 qv = *(const float4*)&q[sd * HID + ch];
  if (k0) { qv.x = 0.f; qv.y = 0.f; qv.z = 0.f; qv.w = 0.f; }
  const float4* wcs4 = (const float4*)wcs;
  const float4* zs4 = (const float4*)zs;
  float4* zsw = (float4*)zs;
  float* nout = sd ? n2o : n1o;
  const int ntiles = N_NODES / GN;
  const int tstride = gridDim.x >> 1;
  for (int t = blockIdx.x >> 1; t < ntiles; t += tstride) {
    int nbase = t * GN;
    const float4* zg = (const float4*)(Z + (size_t)nbase * HID);
    zsw[tid] = zg[tid];
    zsw[tid + 512] = zg[tid + 512];
    __syncthreads();
    float4 a0 = qv, a1 = qv, a2 = qv, a3 = qv;
#pragma unroll 8
    for (int kk = 0; kk < 64; kk += 4) {
      int k = k0 + kk;
      float4 w0 = wcs4[((k + 0) * HID + ch) >> 2];
      float4 w1 = wcs4[((k + 1) * HID + ch) >> 2];
      float4 w2 = wcs4[((k + 2) * HID + ch) >> 2];
      float4 w3 = wcs4[((k + 3) * HID + ch) >> 2];
      float4 z0 = zs4[((nb + 0) * HID + k) >> 2];
      float4 z1 = zs4[((nb + 1) * HID + k) >> 2];
      float4 z2 = zs4[((nb + 2) * HID + k) >> 2];
      float4 z3 = zs4[((nb + 3) * HID + k) >> 2];
      fma4(a0, z0.x, w0); fma4(a0, z0.y, w1); fma4(a0, z0.z, w2); fma4(a0, z0.w, w3);
      fma4(a1, z1.x, w0); fma4(a1, z1.y, w1); fma4(a1, z1.z, w2); fma4(a1, z1.w, w3);
      fma4(a2, z2.x, w0); fma4(a2, z2.y, w1); fma4(a2, z2.z, w2); fma4(a2, z2.w, w3);
      fma4(a3, z3.x, w0); fma4(a3, z3.y, w1); fma4(a3, z3.z, w2); fma4(a3, z3.w, w3);
    }
    // merge k-halves (lane ^ 32 holds the other 64 k's)
    a0.x += __shfl_xor(a0.x, 32); a0.y += __shfl_xor(a0.y, 32);
    a0.z += __shfl_xor(a0.z, 32); a0.w += __shfl_xor(a0.w, 32);
    a1.x += __shfl_xor(a1.x, 32); a1.y += __shfl_xor(a1.y, 32);
    a1.z += __shfl_xor(a1.z, 32); a1.w += __shfl_xor(a1.w, 32);
    a2.x += __shfl_xor(a2.x, 32); a2.y += __shfl_xor(a2.y, 32);
    a2.z += __shfl_xor(a2.z, 32); a2.w += __shfl_xor(a2.w, 32);
    a3.x += __shfl_xor(a3.x, 32); a3.y += __shfl_xor(a3.y, 32);
    a3.z += __shfl_xor(a3.z, 32); a3.w += __shfl_xor(a3.w, 32);
    // quantize to bf16 (RNE), norms from the quantized values
    a0.x = bf_round(a0.x); a0.y = bf_round(a0.y); a0.z = bf_round(a0.z); a0.w = bf_round(a0.w);
    a1.x = bf_round(a1.x); a1.y = bf_round(a1.y); a1.z = bf_round(a1.z); a1.w = bf_round(a1.w);
    a2.x = bf_round(a2.x); a2.y = bf_round(a2.y); a2.z = bf_round(a2.z); a2.w = bf_round(a2.w);
    a3.x = bf_round(a3.x); a3.y = bf_round(a3.y); a3.z = bf_round(a3.z); a3.w = bf_round(a3.w);
    float s0 = a0.x * a0.x + a0.y * a0.y + a0.z * a0.z + a0.w * a0.w;
    float s1 = a1.x * a1.x + a1.y * a1.y + a1.z * a1.z + a1.w * a1.w;
    float s2 = a2.x * a2.x + a2.y * a2.y + a2.z * a2.z + a2.w * a2.w;
    float s3 = a3.x * a3.x + a3.y * a3.y + a3.z * a3.z + a3.w * a3.w;
#pragma unroll
    for (int m = 1; m <= 16; m <<= 1) {
      s0 += __shfl_xor(s0, m);
      s1 += __shfl_xor(s1, m);
      s2 += __shfl_xor(s2, m);
      s3 += __shfl_xor(s3, m);
    }
    if (lane < 32) {
      size_t row = (size_t)(nbase + nb);
      unsigned short* yp = Yb + row * C2 + sd * HID + ch;
      ushort4 p;
      p.x = bf_top(a0.x); p.y = bf_top(a0.y); p.z = bf_top(a0.z); p.w = bf_top(a0.w);
      *(ushort4*)(yp + 0 * C2) = p;
      p.x = bf_top(a1.x); p.y = bf_top(a1.y); p.z = bf_top(a1.z); p.w = bf_top(a1.w);
      *(ushort4*)(yp + 1 * C2) = p;
      p.x = bf_top(a2.x); p.y = bf_top(a2.y); p.z = bf_top(a2.z); p.w = bf_top(a2.w);
      *(ushort4*)(yp + 2 * C2) = p;
      p.x = bf_top(a3.x); p.y = bf_top(a3.y); p.z = bf_top(a3.z); p.w = bf_top(a3.w);
      *(ushort4*)(yp + 3 * C2) = p;
      if (lane == 0) {
        nout[row + 0] = sqrtf(s0);
        nout[row + 1] = sqrtf(s1);
        nout[row + 2] = sqrtf(s2);
        nout[row + 3] = sqrtf(s3);
      }
    }
    __syncthreads();  // zs fully consumed before next stage
  }
}

// ---------------------------------------------------------- per-edge cosine
__global__ __launch_bounds__(256) void edge_kernel(const int* __restrict__ ei,
                                                   const unsigned short* __restrict__ Yb,
                                                   const float* __restrict__ n1,
                                                   const float* __restrict__ n2,
                                                   float* __restrict__ out) {
  int tid = blockIdx.x * blockDim.x + threadIdx.x;
  int g = tid >> 4;
  int l = tid & 15;
  int ngroups = (gridDim.x * blockDim.x) >> 4;
  const uint32* Yw = (const uint32*)Yb;
  for (int e = g; e < N_EDGES; e += ngroups) {
    int i = ei[e], j = ei[N_EDGES + e];
    uint4 ua = *(const uint4*)(Yw + (size_t)i * 128 + l * 4);
    uint4 ub = *(const uint4*)(Yw + (size_t)j * 128 + 64 + l * 4);
    float d = bf_lo(ua.x) * bf_lo(ub.x) + bf_hi(ua.x) * bf_hi(ub.x) +
              bf_lo(ua.y) * bf_lo(ub.y) + bf_hi(ua.y) * bf_hi(ub.y) +
              bf_lo(ua.z) * bf_lo(ub.z) + bf_hi(ua.z) * bf_hi(ub.z) +
              bf_lo(ua.w) * bf_lo(ub.w) + bf_hi(ua.w) * bf_hi(ub.w);
    d += __shfl_xor(d, 8);
    d += __shfl_xor(d, 4);
    d += __shfl_xor(d, 2);
    d += __shfl_xor(d, 1);
    if (l == 0) {
      float nn = n1[i] * n2[j];
      out[e] = (d / fmaxf(nn, 1e-8f) + 1.0f) * 0.5f;
    }
  }
}

// ------------------------------------------------------------------ launch
extern "C" void kernel_launch(void* const* d_in, const int* in_sizes, int n_in,
                              void* d_out, int out_size, void* d_ws, size_t ws_size,
                              hipStream_t stream) {
  const float* x = (const float*)d_in[0];
  const int* ei = (const int*)d_in[1];
  const float* W1 = (const float*)d_in[2];
  const float* b1 = (const float*)d_in[3];
  const float* gamma = (const float*)d_in[4];
  const float* beta = (const float*)d_in[5];
  const float* W2 = (const float*)d_in[6];
  const float* b2 = (const float*)d_in[7];
  float* out = (float*)d_out;

  auto align = [](size_t v) { return (v + 255) & ~(size_t)255; };
  char* ws = (char*)d_ws;
  size_t o_c0 = 0;
  size_t o_c1 = o_c0 + align(N_NODES * sizeof(int));
  size_t o_cend = o_c1 + align(N_NODES * sizeof(int));
  size_t o_sp = o_cend;
  size_t o_s2 = o_sp + align((size_t)ZBLOCKS * 512 * sizeof(float));
  size_t o_P = o_s2 + align((size_t)FB * 512 * sizeof(float));
  size_t o_q = o_P + align(512 * sizeof(float));
  size_t o_n1 = o_q + align(C2 * sizeof(float));
  size_t o_n2 = o_n1 + align(N_NODES * sizeof(float));
  size_t o_Z = o_n2 + align(N_NODES * sizeof(float));
  size_t o_Y = o_Z + align((size_t)N_NODES * HID * sizeof(float));

  int* c0 = (int*)(ws + o_c0);
  int* c1 = (int*)(ws + o_c1);
  float* Sp = (float*)(ws + o_sp);
  float* S2 = (float*)(ws + o_s2);
  float* P = (float*)(ws + o_P);
  float* q = (float*)(ws + o_q);
  float* n1 = (float*)(ws + o_n1);
  float* n2 = (float*)(ws + o_n2);
  float* Z = (float*)(ws + o_Z);
  unsigned short* Yb = (unsigned short*)(ws + o_Y);

  hipMemsetAsync(ws + o_c0, 0, o_cend, stream);
  count_kernel<<<2048, 256, 0, stream>>>(ei, c0, c1);
  zpass_kernel<<<ZBLOCKS, 256, 0, stream>>>(x, W1, b1, c0, c1, Z, Sp);
  finalize_a<<<FB, 512, 0, stream>>>(Sp, S2);
  finalize_b<<<1, 512, 0, stream>>>(S2, gamma, beta, W2, b2, P, q);
  ygemm_kernel<<<512, 512, 0, stream>>>(Z, W2, P, q, Yb, n1, n2);
  edge_kernel<<<2048, 256, 0, stream>>>(ei, Yb, n1, n2, out);
}

// Round 5
// 243.881 us; speedup vs baseline: 2.8936x; 1.2916x over previous
//
#include <hip/hip_runtime.h>
#include <math.h>

#define N_NODES 100000
#define N_PAD   100032        // 1563 * 64 (padded to 64-node tiles)
#define N_EDGES 1000000
#define F_IN 64
#define HID 128
#define C2 256
#define GN 32
#define ZBLOCKS 1024
#define FB 64
#define YGRID 512
#define YTILES 1563

typedef unsigned int uint32;
typedef __bf16 bf16x8 __attribute__((ext_vector_type(8)));
typedef float f32x4 __attribute__((ext_vector_type(4)));

// ---- bf16 helpers (RNE) ----
__device__ __forceinline__ float bf_round(float f) {
  union { float f; uint32 u; } c; c.f = f;
  c.u = (c.u + 0x7fffu + ((c.u >> 16) & 1u)) & 0xffff0000u;
  return c.f;
}
__device__ __forceinline__ unsigned short bf_top(float f) {
  union { float f; uint32 u; } c; c.f = f;
  c.u = c.u + 0x7fffu + ((c.u >> 16) & 1u);
  return (unsigned short)(c.u >> 16);
}
__device__ __forceinline__ float bf_lo(uint32 u) {
  union { uint32 u; float f; } c; c.u = u << 16; return c.f;
}
__device__ __forceinline__ float bf_hi(uint32 u) {
  union { uint32 u; float f; } c; c.u = u & 0xffff0000u; return c.f;
}

// ---------------------------------------------------------------- counts
__global__ __launch_bounds__(256) void count_kernel(const int* __restrict__ ei,
                                                    int* __restrict__ c0,
                                                    int* __restrict__ c1) {
  int stride = gridDim.x * blockDim.x;
  for (int e = blockIdx.x * blockDim.x + threadIdx.x; e < N_EDGES; e += stride) {
    atomicAdd(&c0[ei[e]], 1);
    atomicAdd(&c1[ei[N_EDGES + e]], 1);
  }
}

// ------------------------- Z(bf16) = relu(x@W1+b1) + weighted stat partials
__global__ __launch_bounds__(256, 4) void zpass_kernel(const float* __restrict__ x,
                                                       const float* __restrict__ W1,
                                                       const float* __restrict__ b1,
                                                       const int* __restrict__ c0,
                                                       const int* __restrict__ c1,
                                                       unsigned short* __restrict__ Zb,
                                                       float* __restrict__ Spart) {
  __shared__ float xs[GN * F_IN];  // 8 KB; reused as 4x256 partial buffer at end
  int tid = threadIdx.x;
  int f = tid & 127, h = tid >> 7;
  float wv[F_IN];
#pragma unroll
  for (int k = 0; k < F_IN; ++k) wv[k] = W1[k * HID + f];
  float bb = b1[f];
  float a10 = 0.f, a20 = 0.f, a11 = 0.f, a21 = 0.f;
  float4* xs4 = (float4*)xs;
  const int ntiles = N_NODES / GN;  // 3125
  for (int t = blockIdx.x; t < ntiles; t += ZBLOCKS) {
    int nbase = t * GN;
    __syncthreads();
    const float4* xg = (const float4*)(x + (size_t)nbase * F_IN);
    xs4[tid] = xg[tid];
    xs4[tid + 256] = xg[tid + 256];
    __syncthreads();
#pragma unroll
    for (int nn = h; nn < GN; nn += 2) {
      const float4* xv = (const float4*)(xs + nn * F_IN);
      float z = bb;
#pragma unroll
      for (int kq = 0; kq < F_IN / 4; ++kq) {
        float4 xq = xv[kq];
        z = fmaf(xq.x, wv[4 * kq + 0], z);
        z = fmaf(xq.y, wv[4 * kq + 1], z);
        z = fmaf(xq.z, wv[4 * kq + 2], z);
        z = fmaf(xq.w, wv[4 * kq + 3], z);
      }
      z = fmaxf(z, 0.f);
      int gn = nbase + nn;
      Zb[(size_t)gn * HID + f] = bf_top(z);
      float cc0 = (float)c0[gn], cc1 = (float)c1[gn];
      float z2 = z * z;
      a10 = fmaf(cc0, z, a10);
      a20 = fmaf(cc0, z2, a20);
      a11 = fmaf(cc1, z, a11);
      a21 = fmaf(cc1, z2, a21);
    }
  }
  __syncthreads();
  xs[0 * 256 + h * 128 + f] = a10;
  xs[1 * 256 + h * 128 + f] = a20;
  xs[2 * 256 + h * 128 + f] = a11;
  xs[3 * 256 + h * 128 + f] = a21;
  __syncthreads();
  for (int i = tid; i < 512; i += 256) {
    int st = i >> 7, ff = i & 127;
    Spart[(size_t)blockIdx.x * 512 + i] = xs[st * 256 + ff] + xs[st * 256 + 128 + ff];
  }
}

// ------------------------------------- two-stage deterministic stat reduce
__global__ __launch_bounds__(512) void finalize_a(const float* __restrict__ Spart,
                                                  float* __restrict__ S2) {
  int t = threadIdx.x, b = blockIdx.x;
  float s = 0.f;
  for (int p = b; p < ZBLOCKS; p += FB) s += Spart[(size_t)p * 512 + t];
  S2[(size_t)b * 512 + t] = s;
}

// P[0:128)=scale0, P[256:384)=scale1 ; q[256] = shift@W2 + b2 (both sides)
__global__ __launch_bounds__(512) void finalize_b(const float* __restrict__ S2,
                                                  const float* __restrict__ gamma,
                                                  const float* __restrict__ beta,
                                                  const float* __restrict__ W2,
                                                  const float* __restrict__ b2,
                                                  float* __restrict__ P,
                                                  float* __restrict__ q) {
  __shared__ float S[512];
  __shared__ float sh[256];
  int t = threadIdx.x;
  float s = 0.f;
  for (int b = 0; b < FB; ++b) s += S2[(size_t)b * 512 + t];
  S[t] = s;
  __syncthreads();
  if (t < 128) {
    const float invE = 1.0f / (float)N_EDGES;
    float mu0 = S[t] * invE;
    float v0 = fmaxf(S[128 + t] * invE - mu0 * mu0, 0.f);
    float sc0 = gamma[t] * rsqrtf(v0 + 1e-5f);
    P[t] = sc0;
    sh[t] = beta[t] - mu0 * sc0;
    float mu1 = S[256 + t] * invE;
    float v1 = fmaxf(S[384 + t] * invE - mu1 * mu1, 0.f);
    float sc1 = gamma[t] * rsqrtf(v1 + 1e-5f);
    P[256 + t] = sc1;
    sh[128 + t] = beta[t] - mu1 * sc1;
  }
  __syncthreads();
  if (t < 256) {
    int side = t >> 7, c = t & 127;
    float acc = b2[c];
    for (int ff = 0; ff < HID; ++ff) acc = fmaf(sh[side * 128 + ff], W2[ff * HID + c], acc);
    q[t] = acc;
  }
}

// ---- Wct[col][k] = bf16( W2[k][col&127] * scale[side][k] ), XOR-swizzled ----
__global__ __launch_bounds__(256) void prep_wct(const float* __restrict__ W2,
                                                const float* __restrict__ P,
                                                unsigned short* __restrict__ Wct) {
  int idx = blockIdx.x * 256 + threadIdx.x;  // 0..32767
  int col = idx >> 7, k = idx & 127;
  int side = col >> 7, c = col & 127;
  float v = W2[k * HID + c] * P[side * 256 + k];
  Wct[(col * HID + k) ^ ((col & 7) << 3)] = bf_top(v);
}

// -------------------- MFMA: Y(bf16) = Zbf16 @ Wc(bf16) + q, norms ----------
__global__ __launch_bounds__(512, 4) void ygemm_kernel(const unsigned short* __restrict__ Zb,
                                                       const unsigned short* __restrict__ Wct,
                                                       const float* __restrict__ q,
                                                       unsigned short* __restrict__ Yb,
                                                       float* __restrict__ n1o,
                                                       float* __restrict__ n2o) {
  __shared__ __align__(16) unsigned short wcs[C2 * HID];  // 64 KB, swizzled [col][k]
  __shared__ __align__(16) unsigned short zs[64 * HID];   // 16 KB, swizzled [row][k]
  float* nrmp = (float*)zs;  // aliased AFTER all zs reads of the tile are done
  int tid = threadIdx.x;
  {  // stage Wct (swizzle already baked into the global image)
    const uint4* src = (const uint4*)Wct;
    uint4* dst = (uint4*)wcs;
    for (int c = tid; c < C2 * HID / 8; c += 512) dst[c] = src[c];
  }
  __syncthreads();
  int l = tid & 63, w = tid >> 6;
  int lr = l & 15, lg = l >> 4;
  int rg = w & 1, cg = w >> 1;  // rows rg*32..+32, cols cg*64..+64
  // preload B fragments (constant across all tiles) + bias
  bf16x8 Bf[4][4];
  float qv[4];
#pragma unroll
  for (int cb = 0; cb < 4; ++cb) {
    int col = (cg * 4 + cb) * 16 + lr;
    qv[cb] = q[col];
#pragma unroll
    for (int ks = 0; ks < 4; ++ks) {
      int idx = (col * HID + ks * 32 + lg * 8) ^ ((col & 7) << 3);
      Bf[cb][ks] = *(const bf16x8*)&wcs[idx];
    }
  }
  for (int t = blockIdx.x; t < YTILES; t += YGRID) {
    int nbase = t * 64;
    __syncthreads();  // prev tile's nrmp reads done; safe to overwrite zs
#pragma unroll
    for (int cc = 0; cc < 2; ++cc) {
      int c = tid + cc * 512;
      int row = c >> 4, kc = c & 15;
      uint4 v = *(const uint4*)&Zb[(size_t)(nbase + row) * HID + kc * 8];
      *(uint4*)&zs[(row * HID + kc * 8) ^ ((row & 7) << 3)] = v;
    }
    __syncthreads();
    f32x4 acc[2][4] = {};
#pragma unroll
    for (int ks = 0; ks < 4; ++ks) {
      int r0 = rg * 32 + lr;
      bf16x8 a0 = *(const bf16x8*)&zs[(r0 * HID + ks * 32 + lg * 8) ^ ((lr & 7) << 3)];
      bf16x8 a1 = *(const bf16x8*)&zs[((r0 + 16) * HID + ks * 32 + lg * 8) ^ ((lr & 7) << 3)];
#pragma unroll
      for (int cb = 0; cb < 4; ++cb) {
        acc[0][cb] = __builtin_amdgcn_mfma_f32_16x16x32_bf16(a0, Bf[cb][ks], acc[0][cb], 0, 0, 0);
        acc[1][cb] = __builtin_amdgcn_mfma_f32_16x16x32_bf16(a1, Bf[cb][ks], acc[1][cb], 0, 0, 0);
      }
    }
    __syncthreads();  // all zs reads done; zs region reused as nrmp
    float sq[2][4] = {{0.f, 0.f, 0.f, 0.f}, {0.f, 0.f, 0.f, 0.f}};
#pragma unroll
    for (int nh = 0; nh < 2; ++nh) {
#pragma unroll
      for (int cb = 0; cb < 4; ++cb) {
        int col = (cg * 4 + cb) * 16 + lr;
#pragma unroll
        for (int r = 0; r < 4; ++r) {
          float y = bf_round(acc[nh][cb][r] + qv[cb]);
          sq[nh][r] += y * y;
          int grow = nbase + rg * 32 + nh * 16 + lg * 4 + r;
          if (grow < N_NODES) Yb[(size_t)grow * C2 + col] = bf_top(y);
        }
      }
    }
#pragma unroll
    for (int nh = 0; nh < 2; ++nh)
#pragma unroll
      for (int r = 0; r < 4; ++r) {
        float s = sq[nh][r];
        s += __shfl_xor(s, 1); s += __shfl_xor(s, 2);
        s += __shfl_xor(s, 4); s += __shfl_xor(s, 8);
        sq[nh][r] = s;
      }
    if (lr == 0) {
#pragma unroll
      for (int nh = 0; nh < 2; ++nh)
#pragma unroll
        for (int r = 0; r < 4; ++r)
          nrmp[w * 32 + nh * 16 + lg * 4 + r] = sq[nh][r];
    }
    __syncthreads();
    if (tid < 64) {
      int row = tid, rg2 = row >> 5, rl = row & 31, grow = nbase + row;
      if (grow < N_NODES) {
        n1o[grow] = sqrtf(nrmp[rg2 * 32 + rl] + nrmp[(2 + rg2) * 32 + rl]);
        n2o[grow] = sqrtf(nrmp[(4 + rg2) * 32 + rl] + nrmp[(6 + rg2) * 32 + rl]);
      }
    }
  }
}

// ---------------------------------------------------------- per-edge cosine
__device__ __forceinline__ float dp4(uint4 a, uint4 b) {
  return bf_lo(a.x) * bf_lo(b.x) + bf_hi(a.x) * bf_hi(b.x) +
         bf_lo(a.y) * bf_lo(b.y) + bf_hi(a.y) * bf_hi(b.y) +
         bf_lo(a.z) * bf_lo(b.z) + bf_hi(a.z) * bf_hi(b.z) +
         bf_lo(a.w) * bf_lo(b.w) + bf_hi(a.w) * bf_hi(b.w);
}

__global__ __launch_bounds__(256) void edge_kernel(const int* __restrict__ ei,
                                                   const unsigned short* __restrict__ Yb,
                                                   const float* __restrict__ n1,
                                                   const float* __restrict__ n2,
                                                   float* __restrict__ out) {
  int tid = blockIdx.x * blockDim.x + threadIdx.x;
  int g = tid >> 3, l = tid & 7;
  int ngroups = (gridDim.x * blockDim.x) >> 3;
  const uint32* Yw = (const uint32*)Yb;
  for (int e = g; e < N_EDGES; e += ngroups) {
    int i = ei[e], j = ei[N_EDGES + e];
    const uint4* pa = (const uint4*)(Yw + (size_t)i * 128 + l * 8);
    const uint4* pb = (const uint4*)(Yw + (size_t)j * 128 + 64 + l * 8);
    uint4 a0 = pa[0], a1 = pa[1];
    uint4 b0 = pb[0], b1 = pb[1];
    float d = dp4(a0, b0) + dp4(a1, b1);
    d += __shfl_xor(d, 1);
    d += __shfl_xor(d, 2);
    d += __shfl_xor(d, 4);
    if (l == 0) {
      out[e] = (d / fmaxf(n1[i] * n2[j], 1e-8f) + 1.0f) * 0.5f;
    }
  }
}

// ------------------------------------------------------------------ launch
extern "C" void kernel_launch(void* const* d_in, const int* in_sizes, int n_in,
                              void* d_out, int out_size, void* d_ws, size_t ws_size,
                              hipStream_t stream) {
  const float* x = (const float*)d_in[0];
  const int* ei = (const int*)d_in[1];
  const float* W1 = (const float*)d_in[2];
  const float* b1 = (const float*)d_in[3];
  const float* gamma = (const float*)d_in[4];
  const float* beta = (const float*)d_in[5];
  const float* W2 = (const float*)d_in[6];
  const float* b2 = (const float*)d_in[7];
  float* out = (float*)d_out;

  auto align = [](size_t v) { return (v + 255) & ~(size_t)255; };
  char* ws = (char*)d_ws;
  size_t o_c0 = 0;
  size_t o_c1 = o_c0 + align(N_NODES * sizeof(int));
  size_t o_cend = o_c1 + align(N_NODES * sizeof(int));
  size_t o_sp = o_cend;
  size_t o_s2 = o_sp + align((size_t)ZBLOCKS * 512 * sizeof(float));
  size_t o_P = o_s2 + align((size_t)FB * 512 * sizeof(float));
  size_t o_q = o_P + align(512 * sizeof(float));
  size_t o_wct = o_q + align(C2 * sizeof(float));
  size_t o_n1 = o_wct + align((size_t)C2 * HID * sizeof(unsigned short));
  size_t o_n2 = o_n1 + align(N_NODES * sizeof(float));
  size_t o_Z = o_n2 + align(N_NODES * sizeof(float));
  size_t o_Y = o_Z + align((size_t)N_PAD * HID * sizeof(unsigned short));

  int* c0 = (int*)(ws + o_c0);
  int* c1 = (int*)(ws + o_c1);
  float* Sp = (float*)(ws + o_sp);
  float* S2 = (float*)(ws + o_s2);
  float* P = (float*)(ws + o_P);
  float* q = (float*)(ws + o_q);
  unsigned short* Wct = (unsigned short*)(ws + o_wct);
  float* n1 = (float*)(ws + o_n1);
  float* n2 = (float*)(ws + o_n2);
  unsigned short* Zb = (unsigned short*)(ws + o_Z);
  unsigned short* Yb = (unsigned short*)(ws + o_Y);

  hipMemsetAsync(ws + o_c0, 0, o_cend, stream);
  count_kernel<<<2048, 256, 0, stream>>>(ei, c0, c1);
  zpass_kernel<<<ZBLOCKS, 256, 0, stream>>>(x, W1, b1, c0, c1, Zb, Sp);
  finalize_a<<<FB, 512, 0, stream>>>(Sp, S2);
  finalize_b<<<1, 512, 0, stream>>>(S2, gamma, beta, W2, b2, P, q);
  prep_wct<<<128, 256, 0, stream>>>(W2, P, Wct);
  ygemm_kernel<<<YGRID, 512, 0, stream>>>(Zb, Wct, q, Yb, n1, n2);
  edge_kernel<<<2048, 256, 0, stream>>>(ei, Yb, n1, n2, out);
}

// Round 6
// 199.896 us; speedup vs baseline: 3.5303x; 1.2200x over previous
//
#include <hip/hip_runtime.h>
#include <math.h>

#define N_NODES 100000
#define N_PAD   100032        // 1563 * 64 (padded to 64-node tiles)
#define N_EDGES 1000000
#define F_IN 64
#define HID 128
#define C2 256
#define GN 32
#define ZBLOCKS 1024
#define FB 64
#define YGRID 512
#define YTILES 1563
// histogram count path
#define RANGES 4
#define RSIZE 25000           // nodes per range (4*25000 = 100000)
#define BPR 50                // blocks per range; each scans 1M/50 edges
#define EPB (N_EDGES / BPR)   // 20000

typedef unsigned int uint32;
typedef __bf16 bf16x8 __attribute__((ext_vector_type(8)));
typedef float f32x4 __attribute__((ext_vector_type(4)));

// ---- bf16 helpers (RNE) ----
__device__ __forceinline__ float bf_round(float f) {
  union { float f; uint32 u; } c; c.f = f;
  c.u = (c.u + 0x7fffu + ((c.u >> 16) & 1u)) & 0xffff0000u;
  return c.f;
}
__device__ __forceinline__ unsigned short bf_top(float f) {
  union { float f; uint32 u; } c; c.f = f;
  c.u = c.u + 0x7fffu + ((c.u >> 16) & 1u);
  return (unsigned short)(c.u >> 16);
}
__device__ __forceinline__ float bf_lo(uint32 u) {
  union { uint32 u; float f; } c; c.u = u << 16; return c.f;
}
__device__ __forceinline__ float bf_hi(uint32 u) {
  union { uint32 u; float f; } c; c.u = u & 0xffff0000u; return c.f;
}

// ---------------- counts via LDS histograms (no global atomics) ------------
// Part[(range*BPR + blk)*RSIZE + i]: u32, low16 = c0 count, high16 = c1 count
__global__ __launch_bounds__(256) void hist_kernel(const int* __restrict__ ei,
                                                   uint32* __restrict__ Part) {
  __shared__ uint32 h[RSIZE];  // ~97.7 KB
  int range = blockIdx.x / BPR, blk = blockIdx.x % BPR;
  int lo = range * RSIZE, hi = lo + RSIZE;
  for (int i = threadIdx.x; i < RSIZE; i += 256) h[i] = 0;
  __syncthreads();
  int e0 = blk * EPB;
  for (int e = e0 + threadIdx.x; e < e0 + EPB; e += 256) {
    int i = ei[e], j = ei[N_EDGES + e];
    if (i >= lo && i < hi) atomicAdd(&h[i - lo], 1u);
    if (j >= lo && j < hi) atomicAdd(&h[j - lo], 0x10000u);
  }
  __syncthreads();
  uint32* p = Part + (size_t)blockIdx.x * RSIZE;
  for (int i = threadIdx.x; i < RSIZE; i += 256) p[i] = h[i];
}

__global__ __launch_bounds__(256) void creduce_kernel(const uint32* __restrict__ Part,
                                                      float* __restrict__ c0f,
                                                      float* __restrict__ c1f) {
  int n = blockIdx.x * 256 + threadIdx.x;
  if (n >= N_NODES) return;
  int range = n / RSIZE, i = n - range * RSIZE;
  const uint32* p = Part + (size_t)range * BPR * RSIZE + i;
  uint32 s = 0;
#pragma unroll 10
  for (int b = 0; b < BPR; ++b) s += p[(size_t)b * RSIZE];
  c0f[n] = (float)(s & 0xffffu);
  c1f[n] = (float)(s >> 16);
}

// ------------------------- Z(bf16) = relu(x@W1+b1) + weighted stat partials
__global__ __launch_bounds__(256, 4) void zpass_kernel(const float* __restrict__ x,
                                                       const float* __restrict__ W1,
                                                       const float* __restrict__ b1,
                                                       const float* __restrict__ c0f,
                                                       const float* __restrict__ c1f,
                                                       unsigned short* __restrict__ Zb,
                                                       float* __restrict__ Spart) {
  __shared__ float xs[GN * F_IN];  // 8 KB; reused as 4x256 partial buffer at end
  int tid = threadIdx.x;
  int f = tid & 127, h = tid >> 7;
  float wv[F_IN];
#pragma unroll
  for (int k = 0; k < F_IN; ++k) wv[k] = W1[k * HID + f];
  float bb = b1[f];
  float a10 = 0.f, a20 = 0.f, a11 = 0.f, a21 = 0.f;
  float4* xs4 = (float4*)xs;
  const int ntiles = N_NODES / GN;  // 3125
  for (int t = blockIdx.x; t < ntiles; t += ZBLOCKS) {
    int nbase = t * GN;
    __syncthreads();
    const float4* xg = (const float4*)(x + (size_t)nbase * F_IN);
    xs4[tid] = xg[tid];
    xs4[tid + 256] = xg[tid + 256];
    __syncthreads();
#pragma unroll
    for (int nn = h; nn < GN; nn += 2) {
      const float4* xv = (const float4*)(xs + nn * F_IN);
      float z = bb;
#pragma unroll
      for (int kq = 0; kq < F_IN / 4; ++kq) {
        float4 xq = xv[kq];
        z = fmaf(xq.x, wv[4 * kq + 0], z);
        z = fmaf(xq.y, wv[4 * kq + 1], z);
        z = fmaf(xq.z, wv[4 * kq + 2], z);
        z = fmaf(xq.w, wv[4 * kq + 3], z);
      }
      z = fmaxf(z, 0.f);
      int gn = nbase + nn;
      Zb[(size_t)gn * HID + f] = bf_top(z);
      float cc0 = c0f[gn], cc1 = c1f[gn];
      float z2 = z * z;
      a10 = fmaf(cc0, z, a10);
      a20 = fmaf(cc0, z2, a20);
      a11 = fmaf(cc1, z, a11);
      a21 = fmaf(cc1, z2, a21);
    }
  }
  __syncthreads();
  xs[0 * 256 + h * 128 + f] = a10;
  xs[1 * 256 + h * 128 + f] = a20;
  xs[2 * 256 + h * 128 + f] = a11;
  xs[3 * 256 + h * 128 + f] = a21;
  __syncthreads();
  for (int i = tid; i < 512; i += 256) {
    int st = i >> 7, ff = i & 127;
    Spart[(size_t)blockIdx.x * 512 + i] = xs[st * 256 + ff] + xs[st * 256 + 128 + ff];
  }
}

// ------------------------------------- two-stage deterministic stat reduce
__global__ __launch_bounds__(512) void finalize_a(const float* __restrict__ Spart,
                                                  float* __restrict__ S2) {
  int t = threadIdx.x, b = blockIdx.x;
  float s = 0.f;
  for (int p = b; p < ZBLOCKS; p += FB) s += Spart[(size_t)p * 512 + t];
  S2[(size_t)b * 512 + t] = s;
}

// P[0:128)=scale0, P[256:384)=scale1 ; q[256] = shift@W2 + b2 (both sides)
__global__ __launch_bounds__(512) void finalize_b(const float* __restrict__ S2,
                                                  const float* __restrict__ gamma,
                                                  const float* __restrict__ beta,
                                                  const float* __restrict__ W2,
                                                  const float* __restrict__ b2,
                                                  float* __restrict__ P,
                                                  float* __restrict__ q) {
  __shared__ float S[512];
  __shared__ float sh[256];
  int t = threadIdx.x;
  float s = 0.f;
  for (int b = 0; b < FB; ++b) s += S2[(size_t)b * 512 + t];
  S[t] = s;
  __syncthreads();
  if (t < 128) {
    const float invE = 1.0f / (float)N_EDGES;
    float mu0 = S[t] * invE;
    float v0 = fmaxf(S[128 + t] * invE - mu0 * mu0, 0.f);
    float sc0 = gamma[t] * rsqrtf(v0 + 1e-5f);
    P[t] = sc0;
    sh[t] = beta[t] - mu0 * sc0;
    float mu1 = S[256 + t] * invE;
    float v1 = fmaxf(S[384 + t] * invE - mu1 * mu1, 0.f);
    float sc1 = gamma[t] * rsqrtf(v1 + 1e-5f);
    P[256 + t] = sc1;
    sh[128 + t] = beta[t] - mu1 * sc1;
  }
  __syncthreads();
  if (t < 256) {
    int side = t >> 7, c = t & 127;
    float acc = b2[c];
    for (int ff = 0; ff < HID; ++ff) acc = fmaf(sh[side * 128 + ff], W2[ff * HID + c], acc);
    q[t] = acc;
  }
}

// ---- Wct[col][k] = bf16( W2[k][col&127] * scale[side][k] ), XOR-swizzled ----
__global__ __launch_bounds__(256) void prep_wct(const float* __restrict__ W2,
                                                const float* __restrict__ P,
                                                unsigned short* __restrict__ Wct) {
  int idx = blockIdx.x * 256 + threadIdx.x;  // 0..32767
  int col = idx >> 7, k = idx & 127;
  int side = col >> 7, c = col & 127;
  float v = W2[k * HID + c] * P[side * 256 + k];
  Wct[(col * HID + k) ^ ((col & 7) << 3)] = bf_top(v);
}

// -------------------- MFMA: Y(bf16) = Zbf16 @ Wc(bf16) + q, norms ----------
__global__ __launch_bounds__(512, 4) void ygemm_kernel(const unsigned short* __restrict__ Zb,
                                                       const unsigned short* __restrict__ Wct,
                                                       const float* __restrict__ q,
                                                       unsigned short* __restrict__ Yb,
                                                       float* __restrict__ n1o,
                                                       float* __restrict__ n2o) {
  __shared__ __align__(16) unsigned short wcs[C2 * HID];  // 64 KB, swizzled [col][k]
  __shared__ __align__(16) unsigned short zs[64 * HID];   // 16 KB, swizzled [row][k]
  float* nrmp = (float*)zs;  // aliased AFTER all zs reads of the tile are done
  int tid = threadIdx.x;
  {  // stage Wct (swizzle already baked into the global image)
    const uint4* src = (const uint4*)Wct;
    uint4* dst = (uint4*)wcs;
    for (int c = tid; c < C2 * HID / 8; c += 512) dst[c] = src[c];
  }
  __syncthreads();
  int l = tid & 63, w = tid >> 6;
  int lr = l & 15, lg = l >> 4;
  int rg = w & 1, cg = w >> 1;  // rows rg*32..+32, cols cg*64..+64
  // preload B fragments (constant across all tiles) + bias
  bf16x8 Bf[4][4];
  float qv[4];
#pragma unroll
  for (int cb = 0; cb < 4; ++cb) {
    int col = (cg * 4 + cb) * 16 + lr;
    qv[cb] = q[col];
#pragma unroll
    for (int ks = 0; ks < 4; ++ks) {
      int idx = (col * HID + ks * 32 + lg * 8) ^ ((col & 7) << 3);
      Bf[cb][ks] = *(const bf16x8*)&wcs[idx];
    }
  }
  for (int t = blockIdx.x; t < YTILES; t += YGRID) {
    int nbase = t * 64;
    __syncthreads();  // prev tile's nrmp reads done; safe to overwrite zs
#pragma unroll
    for (int cc = 0; cc < 2; ++cc) {
      int c = tid + cc * 512;
      int row = c >> 4, kc = c & 15;
      uint4 v = *(const uint4*)&Zb[(size_t)(nbase + row) * HID + kc * 8];
      *(uint4*)&zs[(row * HID + kc * 8) ^ ((row & 7) << 3)] = v;
    }
    __syncthreads();
    f32x4 acc[2][4] = {};
#pragma unroll
    for (int ks = 0; ks < 4; ++ks) {
      int r0 = rg * 32 + lr;
      bf16x8 a0 = *(const bf16x8*)&zs[(r0 * HID + ks * 32 + lg * 8) ^ ((lr & 7) << 3)];
      bf16x8 a1 = *(const bf16x8*)&zs[((r0 + 16) * HID + ks * 32 + lg * 8) ^ ((lr & 7) << 3)];
#pragma unroll
      for (int cb = 0; cb < 4; ++cb) {
        acc[0][cb] = __builtin_amdgcn_mfma_f32_16x16x32_bf16(a0, Bf[cb][ks], acc[0][cb], 0, 0, 0);
        acc[1][cb] = __builtin_amdgcn_mfma_f32_16x16x32_bf16(a1, Bf[cb][ks], acc[1][cb], 0, 0, 0);
      }
    }
    __syncthreads();  // all zs reads done; zs region reused as nrmp
    float sq[2][4] = {{0.f, 0.f, 0.f, 0.f}, {0.f, 0.f, 0.f, 0.f}};
#pragma unroll
    for (int nh = 0; nh < 2; ++nh) {
#pragma unroll
      for (int cb = 0; cb < 4; ++cb) {
        int col = (cg * 4 + cb) * 16 + lr;
#pragma unroll
        for (int r = 0; r < 4; ++r) {
          float y = bf_round(acc[nh][cb][r] + qv[cb]);
          sq[nh][r] += y * y;
          int grow = nbase + rg * 32 + nh * 16 + lg * 4 + r;
          if (grow < N_NODES) Yb[(size_t)grow * C2 + col] = bf_top(y);
        }
      }
    }
#pragma unroll
    for (int nh = 0; nh < 2; ++nh)
#pragma unroll
      for (int r = 0; r < 4; ++r) {
        float s = sq[nh][r];
        s += __shfl_xor(s, 1); s += __shfl_xor(s, 2);
        s += __shfl_xor(s, 4); s += __shfl_xor(s, 8);
        sq[nh][r] = s;
      }
    if (lr == 0) {
#pragma unroll
      for (int nh = 0; nh < 2; ++nh)
#pragma unroll
        for (int r = 0; r < 4; ++r)
          nrmp[w * 32 + nh * 16 + lg * 4 + r] = sq[nh][r];
    }
    __syncthreads();
    if (tid < 64) {
      int row = tid, rg2 = row >> 5, rl = row & 31, grow = nbase + row;
      if (grow < N_NODES) {
        n1o[grow] = sqrtf(nrmp[rg2 * 32 + rl] + nrmp[(2 + rg2) * 32 + rl]);
        n2o[grow] = sqrtf(nrmp[(4 + rg2) * 32 + rl] + nrmp[(6 + rg2) * 32 + rl]);
      }
    }
  }
}

// ---------------------------------------------------------- per-edge cosine
__device__ __forceinline__ float dp4(uint4 a, uint4 b) {
  return bf_lo(a.x) * bf_lo(b.x) + bf_hi(a.x) * bf_hi(b.x) +
         bf_lo(a.y) * bf_lo(b.y) + bf_hi(a.y) * bf_hi(b.y) +
         bf_lo(a.z) * bf_lo(b.z) + bf_hi(a.z) * bf_hi(b.z) +
         bf_lo(a.w) * bf_lo(b.w) + bf_hi(a.w) * bf_hi(b.w);
}

__global__ __launch_bounds__(256) void edge_kernel(const int* __restrict__ ei,
                                                   const unsigned short* __restrict__ Yb,
                                                   const float* __restrict__ n1,
                                                   const float* __restrict__ n2,
                                                   float* __restrict__ out) {
  int tid = blockIdx.x * blockDim.x + threadIdx.x;
  int g = tid >> 3, l = tid & 7;
  int ngroups = (gridDim.x * blockDim.x) >> 3;
  const uint32* Yw = (const uint32*)Yb;
  for (int e = g; e < N_EDGES; e += ngroups) {
    int i = ei[e], j = ei[N_EDGES + e];
    const uint4* pa = (const uint4*)(Yw + (size_t)i * 128 + l * 8);
    const uint4* pb = (const uint4*)(Yw + (size_t)j * 128 + 64 + l * 8);
    uint4 a0 = pa[0], a1 = pa[1];
    uint4 b0 = pb[0], b1 = pb[1];
    float d = dp4(a0, b0) + dp4(a1, b1);
    d += __shfl_xor(d, 1);
    d += __shfl_xor(d, 2);
    d += __shfl_xor(d, 4);
    if (l == 0) {
      out[e] = (d / fmaxf(n1[i] * n2[j], 1e-8f) + 1.0f) * 0.5f;
    }
  }
}

// ------------------------------------------------------------------ launch
extern "C" void kernel_launch(void* const* d_in, const int* in_sizes, int n_in,
                              void* d_out, int out_size, void* d_ws, size_t ws_size,
                              hipStream_t stream) {
  const float* x = (const float*)d_in[0];
  const int* ei = (const int*)d_in[1];
  const float* W1 = (const float*)d_in[2];
  const float* b1 = (const float*)d_in[3];
  const float* gamma = (const float*)d_in[4];
  const float* beta = (const float*)d_in[5];
  const float* W2 = (const float*)d_in[6];
  const float* b2 = (const float*)d_in[7];
  float* out = (float*)d_out;

  auto align = [](size_t v) { return (v + 255) & ~(size_t)255; };
  char* ws = (char*)d_ws;
  size_t o_part = 0;
  size_t o_c0 = o_part + align((size_t)RANGES * BPR * RSIZE * sizeof(uint32));
  size_t o_c1 = o_c0 + align(N_NODES * sizeof(float));
  size_t o_sp = o_c1 + align(N_NODES * sizeof(float));
  size_t o_s2 = o_sp + align((size_t)ZBLOCKS * 512 * sizeof(float));
  size_t o_P = o_s2 + align((size_t)FB * 512 * sizeof(float));
  size_t o_q = o_P + align(512 * sizeof(float));
  size_t o_wct = o_q + align(C2 * sizeof(float));
  size_t o_n1 = o_wct + align((size_t)C2 * HID * sizeof(unsigned short));
  size_t o_n2 = o_n1 + align(N_NODES * sizeof(float));
  size_t o_Z = o_n2 + align(N_NODES * sizeof(float));
  size_t o_Y = o_Z + align((size_t)N_PAD * HID * sizeof(unsigned short));

  uint32* Part = (uint32*)(ws + o_part);
  float* c0f = (float*)(ws + o_c0);
  float* c1f = (float*)(ws + o_c1);
  float* Sp = (float*)(ws + o_sp);
  float* S2 = (float*)(ws + o_s2);
  float* P = (float*)(ws + o_P);
  float* q = (float*)(ws + o_q);
  unsigned short* Wct = (unsigned short*)(ws + o_wct);
  float* n1 = (float*)(ws + o_n1);
  float* n2 = (float*)(ws + o_n2);
  unsigned short* Zb = (unsigned short*)(ws + o_Z);
  unsigned short* Yb = (unsigned short*)(ws + o_Y);

  hist_kernel<<<RANGES * BPR, 256, 0, stream>>>(ei, Part);
  creduce_kernel<<<(N_NODES + 255) / 256, 256, 0, stream>>>(Part, c0f, c1f);
  zpass_kernel<<<ZBLOCKS, 256, 0, stream>>>(x, W1, b1, c0f, c1f, Zb, Sp);
  finalize_a<<<FB, 512, 0, stream>>>(Sp, S2);
  finalize_b<<<1, 512, 0, stream>>>(S2, gamma, beta, W2, b2, P, q);
  prep_wct<<<128, 256, 0, stream>>>(W2, P, Wct);
  ygemm_kernel<<<YGRID, 512, 0, stream>>>(Zb, Wct, q, Yb, n1, n2);
  edge_kernel<<<2048, 256, 0, stream>>>(ei, Yb, n1, n2, out);
}

// Round 7
// 168.438 us; speedup vs baseline: 4.1896x; 1.1868x over previous
//
#include <hip/hip_runtime.h>
#include <math.h>

#define N_NODES 100000
#define N_PAD   100032        // 1563 * 64
#define N_EDGES 1000000
#define F_IN 64
#define HID 128
#define C2 256
#define ZT 1563               // 64-node tiles
#define ZGRID 256             // zpass blocks (= Spart rows)
#define FB 64                 // finalize_a blocks
#define YGRID 512
// histogram count path
#define RANGES 4
#define RSIZE 25000
#define BPR 50
#define EPB (N_EDGES / BPR)   // 20000

typedef unsigned int uint32;
typedef __bf16 bf16x8 __attribute__((ext_vector_type(8)));
typedef float f32x4 __attribute__((ext_vector_type(4)));
typedef unsigned short ushort8v __attribute__((ext_vector_type(8)));

// ---- bf16 helpers (RNE) ----
__device__ __forceinline__ unsigned short bf_top(float f) {
  union { float f; uint32 u; } c; c.f = f;
  c.u = c.u + 0x7fffu + ((c.u >> 16) & 1u);
  return (unsigned short)(c.u >> 16);
}
__device__ __forceinline__ float bf_round(float f) {
  union { float f; uint32 u; } c; c.f = f;
  c.u = (c.u + 0x7fffu + ((c.u >> 16) & 1u)) & 0xffff0000u;
  return c.f;
}
__device__ __forceinline__ float bf_lo(uint32 u) {
  union { uint32 u; float f; } c; c.u = u << 16; return c.f;
}
__device__ __forceinline__ float bf_hi(uint32 u) {
  union { uint32 u; float f; } c; c.u = u & 0xffff0000u; return c.f;
}

// ---------------- counts via LDS histograms (no global atomics) ------------
// Part[(range*BPR + blk)*RSIZE + i]: u32, low16 = c0, high16 = c1
__global__ __launch_bounds__(1024) void hist_kernel(const int* __restrict__ ei,
                                                    uint32* __restrict__ Part) {
  __shared__ uint32 h[RSIZE];  // ~97.7 KB
  int range = blockIdx.x / BPR, blk = blockIdx.x % BPR;
  int lo = range * RSIZE, hi = lo + RSIZE;
  for (int i = threadIdx.x; i < RSIZE; i += 1024) h[i] = 0;
  __syncthreads();
  int e0 = blk * EPB;
  for (int e = e0 + threadIdx.x; e < e0 + EPB; e += 1024) {
    int i = ei[e], j = ei[N_EDGES + e];
    if (i >= lo && i < hi) atomicAdd(&h[i - lo], 1u);
    if (j >= lo && j < hi) atomicAdd(&h[j - lo], 0x10000u);
  }
  __syncthreads();
  uint32* p = Part + (size_t)blockIdx.x * RSIZE;
  for (int i = threadIdx.x; i < RSIZE; i += 1024) p[i] = h[i];
}

__global__ __launch_bounds__(256) void creduce_kernel(const uint32* __restrict__ Part,
                                                      float* __restrict__ c0f,
                                                      float* __restrict__ c1f) {
  int n = blockIdx.x * 256 + threadIdx.x;
  if (n >= N_NODES) return;
  int range = n / RSIZE, i = n - range * RSIZE;
  const uint32* p = Part + (size_t)range * BPR * RSIZE + i;
  uint32 s = 0;
#pragma unroll 10
  for (int b = 0; b < BPR; ++b) s += p[(size_t)b * RSIZE];
  c0f[n] = (float)(s & 0xffffu);
  c1f[n] = (float)(s >> 16);
}

// ----------- MFMA zpass: Zfrag = relu(bf16(x)@bf16(W1)+b1), weighted stats --
// Zfrag layout (uint4 units): [tile][rb(4)][ks(4)][lane(64)] — A-fragment-ready
__global__ __launch_bounds__(256) void zpass_kernel(const float* __restrict__ x,
                                                    const float* __restrict__ W1,
                                                    const float* __restrict__ b1,
                                                    const float* __restrict__ c0f,
                                                    const float* __restrict__ c1f,
                                                    uint4* __restrict__ Zfrag,
                                                    float* __restrict__ Spart) {
  __shared__ __align__(16) unsigned short zstage[8192];  // 16 KB frag staging
  float* red = (float*)zstage;                           // 8 KB reuse after loop
  int tid = threadIdx.x;
  int l = tid & 63, w = tid >> 6;
  int lr = l & 15, lg = l >> 4;
  // W1 B-fragments (K=64 -> 2 chunks of 32), 8 col-tiles: 64 VGPRs
  bf16x8 Bf[8][2];
  float b1v[8];
#pragma unroll
  for (int cb = 0; cb < 8; ++cb) {
    int col = cb * 16 + lr;
    b1v[cb] = b1[col];
#pragma unroll
    for (int kc = 0; kc < 2; ++kc) {
      union { ushort8v u; bf16x8 b; } cv;
#pragma unroll
      for (int j = 0; j < 8; ++j) cv.u[j] = bf_top(W1[(kc * 32 + lg * 8 + j) * HID + col]);
      Bf[cb][kc] = cv.b;
    }
  }
  float s10[8] = {}, s20[8] = {}, s11[8] = {}, s21[8] = {};
  for (int t = blockIdx.x; t < ZT; t += ZGRID) {
    int nbase = t * 64;
    int row = nbase + w * 16 + lr;
    bool ok = row < N_NODES;
    bf16x8 A[2];
#pragma unroll
    for (int kc = 0; kc < 2; ++kc) {
      float4 x0 = make_float4(0.f, 0.f, 0.f, 0.f), x1 = x0;
      if (ok) {
        x0 = *(const float4*)&x[(size_t)row * F_IN + kc * 32 + lg * 8];
        x1 = *(const float4*)&x[(size_t)row * F_IN + kc * 32 + lg * 8 + 4];
      }
      union { ushort8v u; bf16x8 b; } cv;
      cv.u[0] = bf_top(x0.x); cv.u[1] = bf_top(x0.y); cv.u[2] = bf_top(x0.z); cv.u[3] = bf_top(x0.w);
      cv.u[4] = bf_top(x1.x); cv.u[5] = bf_top(x1.y); cv.u[6] = bf_top(x1.z); cv.u[7] = bf_top(x1.w);
      A[kc] = cv.b;
    }
    float cc0[4], cc1[4];
#pragma unroll
    for (int r = 0; r < 4; ++r) {
      int node = nbase + w * 16 + lg * 4 + r;
      bool okr = node < N_NODES;
      cc0[r] = okr ? c0f[node] : 0.f;
      cc1[r] = okr ? c1f[node] : 0.f;
    }
    __syncthreads();  // prev tile's copy-out fully read zstage
#pragma unroll
    for (int cb = 0; cb < 8; ++cb) {
      f32x4 acc = {0.f, 0.f, 0.f, 0.f};
      acc = __builtin_amdgcn_mfma_f32_16x16x32_bf16(A[0], Bf[cb][0], acc, 0, 0, 0);
      acc = __builtin_amdgcn_mfma_f32_16x16x32_bf16(A[1], Bf[cb][1], acc, 0, 0, 0);
      int ks = cb >> 1;
      int lamb = ((cb & 1) * 2 + (lr >> 3)) * 16;
#pragma unroll
      for (int r = 0; r < 4; ++r) {
        float z = fmaxf(acc[r] + b1v[cb], 0.f);
        s10[cb] = fmaf(cc0[r], z, s10[cb]);
        s20[cb] = fmaf(cc0[r] * z, z, s20[cb]);
        s11[cb] = fmaf(cc1[r], z, s11[cb]);
        s21[cb] = fmaf(cc1[r] * z, z, s21[cb]);
        int zi = (w * 4 + ks) * 512 + (lamb + lg * 4 + r) * 8 + (lr & 7);
        zi ^= ((zi >> 7) & 1) << 4;  // bank swizzle (byte-bit5 ^= byte-bit8)
        zstage[zi] = bf_top(z);
      }
    }
    __syncthreads();
    const uint4* zs4 = (const uint4*)zstage;
    for (int i = tid; i < 1024; i += 256) {
      int si = i ^ (((i >> 4) & 1) << 1);  // inverse swizzle at uint4 granularity
      Zfrag[(size_t)t * 1024 + i] = zs4[si];
    }
  }
  __syncthreads();
  // stat reduction: over rows (lg groups) then across waves via LDS
#pragma unroll
  for (int cb = 0; cb < 8; ++cb) {
    float a = s10[cb]; a += __shfl_xor(a, 16); a += __shfl_xor(a, 32);
    float b = s20[cb]; b += __shfl_xor(b, 16); b += __shfl_xor(b, 32);
    float c = s11[cb]; c += __shfl_xor(c, 16); c += __shfl_xor(c, 32);
    float d = s21[cb]; d += __shfl_xor(d, 16); d += __shfl_xor(d, 32);
    if (lg == 0) {
      int feat = cb * 16 + lr;
      red[(w * 4 + 0) * 128 + feat] = a;
      red[(w * 4 + 1) * 128 + feat] = b;
      red[(w * 4 + 2) * 128 + feat] = c;
      red[(w * 4 + 3) * 128 + feat] = d;
    }
  }
  __syncthreads();
  for (int o = tid; o < 512; o += 256) {
    int stat = o >> 7, feat = o & 127;
    float s = red[(0 * 4 + stat) * 128 + feat] + red[(1 * 4 + stat) * 128 + feat] +
              red[(2 * 4 + stat) * 128 + feat] + red[(3 * 4 + stat) * 128 + feat];
    Spart[(size_t)blockIdx.x * 512 + o] = s;
  }
}

// ------------------------------------- two-stage deterministic stat reduce
__global__ __launch_bounds__(512) void finalize_a(const float* __restrict__ Spart,
                                                  float* __restrict__ S2) {
  int t = threadIdx.x, b = blockIdx.x;
  float s = 0.f;
  for (int p = b; p < ZGRID; p += FB) s += Spart[(size_t)p * 512 + t];
  S2[(size_t)b * 512 + t] = s;
}

// scale/shift -> q[256] = shift@W2+b2 ; Wct[col][k] = bf16(W2[k][c]*scale), swizzled
__global__ __launch_bounds__(512) void finalize_b(const float* __restrict__ S2,
                                                  const float* __restrict__ gamma,
                                                  const float* __restrict__ beta,
                                                  const float* __restrict__ W2,
                                                  const float* __restrict__ b2,
                                                  float* __restrict__ q,
                                                  unsigned short* __restrict__ Wct) {
  __shared__ float S[512];
  __shared__ float sh[256];
  __shared__ float scs[256];
  int t = threadIdx.x;
  float s = 0.f;
  for (int b = 0; b < FB; ++b) s += S2[(size_t)b * 512 + t];
  S[t] = s;
  __syncthreads();
  if (t < 128) {
    const float invE = 1.0f / (float)N_EDGES;
    float mu0 = S[t] * invE;
    float v0 = fmaxf(S[128 + t] * invE - mu0 * mu0, 0.f);
    float sc0 = gamma[t] * rsqrtf(v0 + 1e-5f);
    scs[t] = sc0;
    sh[t] = beta[t] - mu0 * sc0;
    float mu1 = S[256 + t] * invE;
    float v1 = fmaxf(S[384 + t] * invE - mu1 * mu1, 0.f);
    float sc1 = gamma[t] * rsqrtf(v1 + 1e-5f);
    scs[128 + t] = sc1;
    sh[128 + t] = beta[t] - mu1 * sc1;
  }
  __syncthreads();
  if (t < 256) {
    int side = t >> 7, c = t & 127;
    float acc = b2[c];
    for (int ff = 0; ff < HID; ++ff) acc = fmaf(sh[side * 128 + ff], W2[ff * HID + c], acc);
    q[t] = acc;
  }
  for (int i = t; i < C2 * HID; i += 512) {
    int col = i >> 7, k = i & 127;
    int side = col >> 7, c = col & 127;
    float v = W2[k * HID + c] * scs[side * 128 + k];
    Wct[(col * HID + k) ^ ((col & 7) << 3)] = bf_top(v);
  }
}

// -------------------- MFMA: Y(bf16) = Zfrag @ Wc(bf16) + q, norms ----------
__global__ __launch_bounds__(512, 4) void ygemm_kernel(const uint4* __restrict__ Zfrag,
                                                       const unsigned short* __restrict__ Wct,
                                                       const float* __restrict__ q,
                                                       unsigned short* __restrict__ Yb,
                                                       float* __restrict__ n1o,
                                                       float* __restrict__ n2o) {
  __shared__ __align__(16) unsigned short wcs[C2 * HID];  // 64 KB swizzled [col][k]
  __shared__ float nrm2[2][256];
  int tid = threadIdx.x;
  {
    const uint4* src = (const uint4*)Wct;
    uint4* dst = (uint4*)wcs;
    for (int c = tid; c < C2 * HID / 8; c += 512) dst[c] = src[c];
  }
  __syncthreads();
  int l = tid & 63, w = tid >> 6;
  int lr = l & 15, lg = l >> 4;
  int rg = w & 1, cg = w >> 1;
  bf16x8 Bf[4][4];
  float qv[4];
#pragma unroll
  for (int cb = 0; cb < 4; ++cb) {
    int col = (cg * 4 + cb) * 16 + lr;
    qv[cb] = q[col];
#pragma unroll
    for (int ks = 0; ks < 4; ++ks) {
      int idx = (col * HID + ks * 32 + lg * 8) ^ ((col & 7) << 3);
      Bf[cb][ks] = *(const bf16x8*)&wcs[idx];
    }
  }
  int p = 0;
  for (int t = blockIdx.x; t < ZT; t += YGRID, p ^= 1) {
    int nbase = t * 64;
    f32x4 acc[2][4] = {};
#pragma unroll
    for (int ks = 0; ks < 4; ++ks) {
      union { uint4 u; bf16x8 b; } A0, A1;
      A0.u = Zfrag[((size_t)t * 16 + rg * 8 + ks) * 64 + l];
      A1.u = Zfrag[((size_t)t * 16 + rg * 8 + 4 + ks) * 64 + l];
#pragma unroll
      for (int cb = 0; cb < 4; ++cb) {
        acc[0][cb] = __builtin_amdgcn_mfma_f32_16x16x32_bf16(A0.b, Bf[cb][ks], acc[0][cb], 0, 0, 0);
        acc[1][cb] = __builtin_amdgcn_mfma_f32_16x16x32_bf16(A1.b, Bf[cb][ks], acc[1][cb], 0, 0, 0);
      }
    }
    float sq[2][4] = {{0.f, 0.f, 0.f, 0.f}, {0.f, 0.f, 0.f, 0.f}};
#pragma unroll
    for (int nh = 0; nh < 2; ++nh) {
#pragma unroll
      for (int cb = 0; cb < 4; ++cb) {
        int col = (cg * 4 + cb) * 16 + lr;
#pragma unroll
        for (int r = 0; r < 4; ++r) {
          float y = bf_round(acc[nh][cb][r] + qv[cb]);
          sq[nh][r] += y * y;
          int grow = nbase + rg * 32 + nh * 16 + lg * 4 + r;
          if (grow < N_NODES) Yb[(size_t)grow * C2 + col] = bf_top(y);
        }
      }
    }
#pragma unroll
    for (int nh = 0; nh < 2; ++nh)
#pragma unroll
      for (int r = 0; r < 4; ++r) {
        float s = sq[nh][r];
        s += __shfl_xor(s, 1); s += __shfl_xor(s, 2);
        s += __shfl_xor(s, 4); s += __shfl_xor(s, 8);
        sq[nh][r] = s;
      }
    if (lr == 0) {
#pragma unroll
      for (int nh = 0; nh < 2; ++nh)
#pragma unroll
        for (int r = 0; r < 4; ++r)
          nrm2[p][w * 32 + nh * 16 + lg * 4 + r] = sq[nh][r];
    }
    __syncthreads();
    if (tid < 64) {
      int row = tid, rg2 = row >> 5, rl = row & 31, grow = nbase + row;
      if (grow < N_NODES) {
        n1o[grow] = sqrtf(nrm2[p][rg2 * 32 + rl] + nrm2[p][(2 + rg2) * 32 + rl]);
        n2o[grow] = sqrtf(nrm2[p][(4 + rg2) * 32 + rl] + nrm2[p][(6 + rg2) * 32 + rl]);
      }
    }
  }
}

// ---------------------------------------------------------- per-edge cosine
__device__ __forceinline__ float dp4(uint4 a, uint4 b) {
  return bf_lo(a.x) * bf_lo(b.x) + bf_hi(a.x) * bf_hi(b.x) +
         bf_lo(a.y) * bf_lo(b.y) + bf_hi(a.y) * bf_hi(b.y) +
         bf_lo(a.z) * bf_lo(b.z) + bf_hi(a.z) * bf_hi(b.z) +
         bf_lo(a.w) * bf_lo(b.w) + bf_hi(a.w) * bf_hi(b.w);
}

__global__ __launch_bounds__(256) void edge_kernel(const int* __restrict__ ei,
                                                   const unsigned short* __restrict__ Yb,
                                                   const float* __restrict__ n1,
                                                   const float* __restrict__ n2,
                                                   float* __restrict__ out) {
  int tid = blockIdx.x * blockDim.x + threadIdx.x;
  int g = tid >> 3, ls = tid & 7;
  int ng = (gridDim.x * blockDim.x) >> 3;
  const uint32* Yw = (const uint32*)Yb;
  for (int e = g; e < N_EDGES; e += 2 * ng) {
    int e2 = e + ng;
    bool h2 = e2 < N_EDGES;
    int i1 = ei[e], j1 = ei[N_EDGES + e];
    int i2 = h2 ? ei[e2] : i1, j2 = h2 ? ei[N_EDGES + e2] : j1;
    const uint4* pa1 = (const uint4*)(Yw + (size_t)i1 * 128 + ls * 8);
    const uint4* pb1 = (const uint4*)(Yw + (size_t)j1 * 128 + 64 + ls * 8);
    const uint4* pa2 = (const uint4*)(Yw + (size_t)i2 * 128 + ls * 8);
    const uint4* pb2 = (const uint4*)(Yw + (size_t)j2 * 128 + 64 + ls * 8);
    uint4 a10 = pa1[0], a11 = pa1[1], b10 = pb1[0], b11 = pb1[1];
    uint4 a20 = pa2[0], a21 = pa2[1], b20 = pb2[0], b21 = pb2[1];
    float d1 = dp4(a10, b10) + dp4(a11, b11);
    float d2 = dp4(a20, b20) + dp4(a21, b21);
    d1 += __shfl_xor(d1, 1); d1 += __shfl_xor(d1, 2); d1 += __shfl_xor(d1, 4);
    d2 += __shfl_xor(d2, 1); d2 += __shfl_xor(d2, 2); d2 += __shfl_xor(d2, 4);
    if (ls == 0) {
      out[e] = (d1 / fmaxf(n1[i1] * n2[j1], 1e-8f) + 1.0f) * 0.5f;
      if (h2) out[e2] = (d2 / fmaxf(n1[i2] * n2[j2], 1e-8f) + 1.0f) * 0.5f;
    }
  }
}

// ------------------------------------------------------------------ launch
extern "C" void kernel_launch(void* const* d_in, const int* in_sizes, int n_in,
                              void* d_out, int out_size, void* d_ws, size_t ws_size,
                              hipStream_t stream) {
  const float* x = (const float*)d_in[0];
  const int* ei = (const int*)d_in[1];
  const float* W1 = (const float*)d_in[2];
  const float* b1 = (const float*)d_in[3];
  const float* gamma = (const float*)d_in[4];
  const float* beta = (const float*)d_in[5];
  const float* W2 = (const float*)d_in[6];
  const float* b2 = (const float*)d_in[7];
  float* out = (float*)d_out;

  auto align = [](size_t v) { return (v + 255) & ~(size_t)255; };
  char* ws = (char*)d_ws;
  size_t o_part = 0;
  size_t o_c0 = o_part + align((size_t)RANGES * BPR * RSIZE * sizeof(uint32));
  size_t o_c1 = o_c0 + align(N_NODES * sizeof(float));
  size_t o_sp = o_c1 + align(N_NODES * sizeof(float));
  size_t o_s2 = o_sp + align((size_t)ZGRID * 512 * sizeof(float));
  size_t o_q = o_s2 + align((size_t)FB * 512 * sizeof(float));
  size_t o_wct = o_q + align(C2 * sizeof(float));
  size_t o_n1 = o_wct + align((size_t)C2 * HID * sizeof(unsigned short));
  size_t o_n2 = o_n1 + align(N_NODES * sizeof(float));
  size_t o_Z = o_n2 + align(N_NODES * sizeof(float));
  size_t o_Y = o_Z + align((size_t)ZT * 1024 * sizeof(uint4));

  uint32* Part = (uint32*)(ws + o_part);
  float* c0f = (float*)(ws + o_c0);
  float* c1f = (float*)(ws + o_c1);
  float* Sp = (float*)(ws + o_sp);
  float* S2 = (float*)(ws + o_s2);
  float* q = (float*)(ws + o_q);
  unsigned short* Wct = (unsigned short*)(ws + o_wct);
  float* n1 = (float*)(ws + o_n1);
  float* n2 = (float*)(ws + o_n2);
  uint4* Zfrag = (uint4*)(ws + o_Z);
  unsigned short* Yb = (unsigned short*)(ws + o_Y);

  hist_kernel<<<RANGES * BPR, 1024, 0, stream>>>(ei, Part);
  creduce_kernel<<<(N_NODES + 255) / 256, 256, 0, stream>>>(Part, c0f, c1f);
  zpass_kernel<<<ZGRID, 256, 0, stream>>>(x, W1, b1, c0f, c1f, Zfrag, Sp);
  finalize_a<<<FB, 512, 0, stream>>>(Sp, S2);
  finalize_b<<<1, 512, 0, stream>>>(S2, gamma, beta, W2, b2, q, Wct);
  ygemm_kernel<<<YGRID, 512, 0, stream>>>(Zfrag, Wct, q, Yb, n1, n2);
  edge_kernel<<<2048, 256, 0, stream>>>(ei, Yb, n1, n2, out);
}

// Round 8
// 134.941 us; speedup vs baseline: 5.2296x; 1.2482x over previous
//
#include <hip/hip_runtime.h>
#include <math.h>

#define N_NODES 100000
#define N_EDGES 1000000
#define F_IN 64
#define HID 128
#define C2 256
#define ZT 1563               // 64-node tiles
#define ZGRID 256             // zpass blocks (= Spart rows)
#define FB 64                 // finalize_a blocks
#define YGRID 512
// histogram count path
#define RANGES 4
#define RSIZE 25000
#define BPR 50
#define EPB (N_EDGES / BPR)   // 20000

typedef unsigned int uint32;
typedef __bf16 bf16x8 __attribute__((ext_vector_type(8)));
typedef float f32x4 __attribute__((ext_vector_type(4)));
typedef unsigned short ushort8v __attribute__((ext_vector_type(8)));

// ---- bf16 helpers (RNE) ----
__device__ __forceinline__ unsigned short bf_top(float f) {
  union { float f; uint32 u; } c; c.f = f;
  c.u = c.u + 0x7fffu + ((c.u >> 16) & 1u);
  return (unsigned short)(c.u >> 16);
}

// ---- int8 dot4 (HW if available) ----
#if defined(__has_builtin)
#if __has_builtin(__builtin_amdgcn_sdot4)
#define SDOT4(a, b, c) __builtin_amdgcn_sdot4((int)(a), (int)(b), (c), false)
#endif
#endif
#ifndef SDOT4
__device__ __forceinline__ int sdot4_sw(uint32 a, uint32 b, int c) {
#pragma unroll
  for (int k = 0; k < 4; ++k)
    c += (int)(signed char)(a >> (8 * k)) * (int)(signed char)(b >> (8 * k));
  return c;
}
#define SDOT4(a, b, c) sdot4_sw(a, b, c)
#endif

// ---------------- counts via LDS histograms (no global atomics) ------------
__global__ __launch_bounds__(1024) void hist_kernel(const int* __restrict__ ei,
                                                    uint32* __restrict__ Part) {
  __shared__ uint32 h[RSIZE];  // ~97.7 KB
  int range = blockIdx.x / BPR, blk = blockIdx.x % BPR;
  int lo = range * RSIZE, hi = lo + RSIZE;
  for (int i = threadIdx.x; i < RSIZE; i += 1024) h[i] = 0;
  __syncthreads();
  int e0 = blk * EPB;
  for (int e = e0 + threadIdx.x; e < e0 + EPB; e += 1024) {
    int i = ei[e], j = ei[N_EDGES + e];
    if (i >= lo && i < hi) atomicAdd(&h[i - lo], 1u);
    if (j >= lo && j < hi) atomicAdd(&h[j - lo], 0x10000u);
  }
  __syncthreads();
  uint32* p = Part + (size_t)blockIdx.x * RSIZE;
  for (int i = threadIdx.x; i < RSIZE; i += 1024) p[i] = h[i];
}

__global__ __launch_bounds__(256) void creduce_kernel(const uint32* __restrict__ Part,
                                                      float* __restrict__ c0f,
                                                      float* __restrict__ c1f) {
  int n = blockIdx.x * 256 + threadIdx.x;
  if (n >= N_NODES) return;
  int range = n / RSIZE, i = n - range * RSIZE;
  const uint32* p = Part + (size_t)range * BPR * RSIZE + i;
  uint32 s = 0;
#pragma unroll 10
  for (int b = 0; b < BPR; ++b) s += p[(size_t)b * RSIZE];
  c0f[n] = (float)(s & 0xffffu);
  c1f[n] = (float)(s >> 16);
}

// ----------- MFMA zpass: Zfrag = relu(bf16(x)@bf16(W1)+b1), weighted stats --
__global__ __launch_bounds__(256) void zpass_kernel(const float* __restrict__ x,
                                                    const float* __restrict__ W1,
                                                    const float* __restrict__ b1,
                                                    const float* __restrict__ c0f,
                                                    const float* __restrict__ c1f,
                                                    uint4* __restrict__ Zfrag,
                                                    float* __restrict__ Spart) {
  __shared__ __align__(16) unsigned short zstage[8192];  // 16 KB frag staging
  float* red = (float*)zstage;                           // 8 KB reuse after loop
  int tid = threadIdx.x;
  int l = tid & 63, w = tid >> 6;
  int lr = l & 15, lg = l >> 4;
  bf16x8 Bf[8][2];
  float b1v[8];
#pragma unroll
  for (int cb = 0; cb < 8; ++cb) {
    int col = cb * 16 + lr;
    b1v[cb] = b1[col];
#pragma unroll
    for (int kc = 0; kc < 2; ++kc) {
      union { ushort8v u; bf16x8 b; } cv;
#pragma unroll
      for (int j = 0; j < 8; ++j) cv.u[j] = bf_top(W1[(kc * 32 + lg * 8 + j) * HID + col]);
      Bf[cb][kc] = cv.b;
    }
  }
  float s10[8] = {}, s20[8] = {}, s11[8] = {}, s21[8] = {};
  for (int t = blockIdx.x; t < ZT; t += ZGRID) {
    int nbase = t * 64;
    int row = nbase + w * 16 + lr;
    bool ok = row < N_NODES;
    bf16x8 A[2];
#pragma unroll
    for (int kc = 0; kc < 2; ++kc) {
      float4 x0 = make_float4(0.f, 0.f, 0.f, 0.f), x1 = x0;
      if (ok) {
        x0 = *(const float4*)&x[(size_t)row * F_IN + kc * 32 + lg * 8];
        x1 = *(const float4*)&x[(size_t)row * F_IN + kc * 32 + lg * 8 + 4];
      }
      union { ushort8v u; bf16x8 b; } cv;
      cv.u[0] = bf_top(x0.x); cv.u[1] = bf_top(x0.y); cv.u[2] = bf_top(x0.z); cv.u[3] = bf_top(x0.w);
      cv.u[4] = bf_top(x1.x); cv.u[5] = bf_top(x1.y); cv.u[6] = bf_top(x1.z); cv.u[7] = bf_top(x1.w);
      A[kc] = cv.b;
    }
    float cc0[4], cc1[4];
#pragma unroll
    for (int r = 0; r < 4; ++r) {
      int node = nbase + w * 16 + lg * 4 + r;
      bool okr = node < N_NODES;
      cc0[r] = okr ? c0f[node] : 0.f;
      cc1[r] = okr ? c1f[node] : 0.f;
    }
    __syncthreads();
#pragma unroll
    for (int cb = 0; cb < 8; ++cb) {
      f32x4 acc = {0.f, 0.f, 0.f, 0.f};
      acc = __builtin_amdgcn_mfma_f32_16x16x32_bf16(A[0], Bf[cb][0], acc, 0, 0, 0);
      acc = __builtin_amdgcn_mfma_f32_16x16x32_bf16(A[1], Bf[cb][1], acc, 0, 0, 0);
      int ks = cb >> 1;
      int lamb = ((cb & 1) * 2 + (lr >> 3)) * 16;
#pragma unroll
      for (int r = 0; r < 4; ++r) {
        float z = fmaxf(acc[r] + b1v[cb], 0.f);
        s10[cb] = fmaf(cc0[r], z, s10[cb]);
        s20[cb] = fmaf(cc0[r] * z, z, s20[cb]);
        s11[cb] = fmaf(cc1[r], z, s11[cb]);
        s21[cb] = fmaf(cc1[r] * z, z, s21[cb]);
        int zi = (w * 4 + ks) * 512 + (lamb + lg * 4 + r) * 8 + (lr & 7);
        zi ^= ((zi >> 7) & 1) << 4;
        zstage[zi] = bf_top(z);
      }
    }
    __syncthreads();
    const uint4* zs4 = (const uint4*)zstage;
    for (int i = tid; i < 1024; i += 256) {
      int si = i ^ (((i >> 4) & 1) << 1);
      Zfrag[(size_t)t * 1024 + i] = zs4[si];
    }
  }
  __syncthreads();
#pragma unroll
  for (int cb = 0; cb < 8; ++cb) {
    float a = s10[cb]; a += __shfl_xor(a, 16); a += __shfl_xor(a, 32);
    float b = s20[cb]; b += __shfl_xor(b, 16); b += __shfl_xor(b, 32);
    float c = s11[cb]; c += __shfl_xor(c, 16); c += __shfl_xor(c, 32);
    float d = s21[cb]; d += __shfl_xor(d, 16); d += __shfl_xor(d, 32);
    if (lg == 0) {
      int feat = cb * 16 + lr;
      red[(w * 4 + 0) * 128 + feat] = a;
      red[(w * 4 + 1) * 128 + feat] = b;
      red[(w * 4 + 2) * 128 + feat] = c;
      red[(w * 4 + 3) * 128 + feat] = d;
    }
  }
  __syncthreads();
  for (int o = tid; o < 512; o += 256) {
    int stat = o >> 7, feat = o & 127;
    float s = red[(0 * 4 + stat) * 128 + feat] + red[(1 * 4 + stat) * 128 + feat] +
              red[(2 * 4 + stat) * 128 + feat] + red[(3 * 4 + stat) * 128 + feat];
    Spart[(size_t)blockIdx.x * 512 + o] = s;
  }
}

// ------------------------------------- two-stage deterministic stat reduce
__global__ __launch_bounds__(512) void finalize_a(const float* __restrict__ Spart,
                                                  float* __restrict__ S2) {
  int t = threadIdx.x, b = blockIdx.x;
  float s = 0.f;
  for (int p = b; p < ZGRID; p += FB) s += Spart[(size_t)p * 512 + t];
  S2[(size_t)b * 512 + t] = s;
}

__global__ __launch_bounds__(512) void finalize_b(const float* __restrict__ S2,
                                                  const float* __restrict__ gamma,
                                                  const float* __restrict__ beta,
                                                  const float* __restrict__ W2,
                                                  const float* __restrict__ b2,
                                                  float* __restrict__ q,
                                                  unsigned short* __restrict__ Wct) {
  __shared__ float S[512];
  __shared__ float sh[256];
  __shared__ float scs[256];
  int t = threadIdx.x;
  float s = 0.f;
  for (int b = 0; b < FB; ++b) s += S2[(size_t)b * 512 + t];
  S[t] = s;
  __syncthreads();
  if (t < 128) {
    const float invE = 1.0f / (float)N_EDGES;
    float mu0 = S[t] * invE;
    float v0 = fmaxf(S[128 + t] * invE - mu0 * mu0, 0.f);
    float sc0 = gamma[t] * rsqrtf(v0 + 1e-5f);
    scs[t] = sc0;
    sh[t] = beta[t] - mu0 * sc0;
    float mu1 = S[256 + t] * invE;
    float v1 = fmaxf(S[384 + t] * invE - mu1 * mu1, 0.f);
    float sc1 = gamma[t] * rsqrtf(v1 + 1e-5f);
    scs[128 + t] = sc1;
    sh[128 + t] = beta[t] - mu1 * sc1;
  }
  __syncthreads();
  if (t < 256) {
    int side = t >> 7, c = t & 127;
    float acc = b2[c];
    for (int ff = 0; ff < HID; ++ff) acc = fmaf(sh[side * 128 + ff], W2[ff * HID + c], acc);
    q[t] = acc;
  }
  for (int i = t; i < C2 * HID; i += 512) {
    int col = i >> 7, k = i & 127;
    int side = col >> 7, c = col & 127;
    float v = W2[k * HID + c] * scs[side * 128 + k];
    Wct[(col * HID + k) ^ ((col & 7) << 3)] = bf_top(v);
  }
}

// ---- MFMA ygemm: Yq(int8, per-row-side scaled) = Zfrag @ Wc + q; g = 1/||q|| ----
// Yq byte layout per row (256 B): side*128 + (cg&1)*64 + lr*4 + cb  (same
// column permutation both sides -> dot/cos invariant).
__global__ __launch_bounds__(512) void ygemm_kernel(const uint4* __restrict__ Zfrag,
                                                    const unsigned short* __restrict__ Wct,
                                                    const float* __restrict__ q,
                                                    uint32* __restrict__ Yq,
                                                    float* __restrict__ g0o,
                                                    float* __restrict__ g1o) {
  __shared__ __align__(16) unsigned short wcs[C2 * HID];  // 64 KB swizzled [col][k]
  __shared__ float maxb[256];
  __shared__ int sqb[256];
  int tid = threadIdx.x;
  {
    const uint4* src = (const uint4*)Wct;
    uint4* dst = (uint4*)wcs;
    for (int c = tid; c < C2 * HID / 8; c += 512) dst[c] = src[c];
  }
  __syncthreads();
  int l = tid & 63, w = tid >> 6;
  int lr = l & 15, lg = l >> 4;
  int rg = w & 1, cg = w >> 1;
  int side = cg >> 1, cgl = cg & 1;
  bf16x8 Bf[4][4];
  float qv[4];
#pragma unroll
  for (int cb = 0; cb < 4; ++cb) {
    int col = (cg * 4 + cb) * 16 + lr;
    qv[cb] = q[col];
#pragma unroll
    for (int ks = 0; ks < 4; ++ks) {
      int idx = (col * HID + ks * 32 + lg * 8) ^ ((col & 7) << 3);
      Bf[cb][ks] = *(const bf16x8*)&wcs[idx];
    }
  }
  int t = blockIdx.x;
  uint4 Ac[8];
  if (t < ZT) {
#pragma unroll
    for (int u = 0; u < 8; ++u) Ac[u] = Zfrag[((size_t)t * 16 + rg * 8 + u) * 64 + l];
  }
  for (; t < ZT; t += YGRID) {
    int nbase = t * 64;
    int tn = t + YGRID;
    uint4 An[8];
    if (tn < ZT) {
#pragma unroll
      for (int u = 0; u < 8; ++u) An[u] = Zfrag[((size_t)tn * 16 + rg * 8 + u) * 64 + l];
    }
    f32x4 acc[2][4] = {};
#pragma unroll
    for (int ks = 0; ks < 4; ++ks) {
      union { uint4 u; bf16x8 b; } A0, A1;
      A0.u = Ac[ks];
      A1.u = Ac[4 + ks];
#pragma unroll
      for (int cb = 0; cb < 4; ++cb) {
        acc[0][cb] = __builtin_amdgcn_mfma_f32_16x16x32_bf16(A0.b, Bf[cb][ks], acc[0][cb], 0, 0, 0);
        acc[1][cb] = __builtin_amdgcn_mfma_f32_16x16x32_bf16(A1.b, Bf[cb][ks], acc[1][cb], 0, 0, 0);
      }
    }
    // --- epilogue: bias, per-(row,side) absmax ---
    float ym[2][4];
#pragma unroll
    for (int nh = 0; nh < 2; ++nh)
#pragma unroll
      for (int r = 0; r < 4; ++r) {
        float m = 0.f;
#pragma unroll
        for (int cb = 0; cb < 4; ++cb) {
          float y = acc[nh][cb][r] + qv[cb];
          acc[nh][cb][r] = y;
          m = fmaxf(m, fabsf(y));
        }
#pragma unroll
        for (int s = 1; s <= 8; s <<= 1) m = fmaxf(m, __shfl_xor(m, s));
        ym[nh][r] = m;
      }
    if (lr == 0) {
#pragma unroll
      for (int nh = 0; nh < 2; ++nh)
#pragma unroll
        for (int r = 0; r < 4; ++r) maxb[w * 32 + nh * 16 + lg * 4 + r] = ym[nh][r];
    }
    __syncthreads();
    // --- combined max -> quantize, pack, write; Σq² partials ---
    int sqi[2][4];
    uint32 qpack[2][4];
#pragma unroll
    for (int nh = 0; nh < 2; ++nh)
#pragma unroll
      for (int r = 0; r < 4; ++r) {
        int ro = nh * 16 + lg * 4 + r;
        float cmax = fmaxf(maxb[(side * 4 + rg) * 32 + ro], maxb[(side * 4 + rg + 2) * 32 + ro]);
        float inv = cmax > 0.f ? 127.f / cmax : 0.f;
        int ssum = 0;
        uint32 pk = 0;
#pragma unroll
        for (int cb = 0; cb < 4; ++cb) {
          int qi = (int)rintf(acc[nh][cb][r] * inv);
          ssum += qi * qi;
          pk |= ((uint32)(qi & 0xff)) << (8 * cb);
        }
        sqi[nh][r] = ssum;
        qpack[nh][r] = pk;
      }
#pragma unroll
    for (int nh = 0; nh < 2; ++nh)
#pragma unroll
      for (int r = 0; r < 4; ++r) {
        int grow = nbase + rg * 32 + nh * 16 + lg * 4 + r;
        if (grow < N_NODES)
          Yq[(size_t)grow * 64 + side * 32 + cgl * 16 + lr] = qpack[nh][r];
      }
#pragma unroll
    for (int nh = 0; nh < 2; ++nh)
#pragma unroll
      for (int r = 0; r < 4; ++r) {
        int s = sqi[nh][r];
#pragma unroll
        for (int m = 1; m <= 8; m <<= 1) s += __shfl_xor(s, m);
        sqi[nh][r] = s;
      }
    if (lr == 0) {
#pragma unroll
      for (int nh = 0; nh < 2; ++nh)
#pragma unroll
        for (int r = 0; r < 4; ++r) sqb[w * 32 + nh * 16 + lg * 4 + r] = sqi[nh][r];
    }
    __syncthreads();
    if (tid < 128) {
      int sd = tid >> 6, row = tid & 63;
      int rg2 = row >> 5, ro = row & 31;
      int sum = sqb[(sd * 4 + rg2) * 32 + ro] + sqb[(sd * 4 + rg2 + 2) * 32 + ro];
      int grow = nbase + row;
      if (grow < N_NODES) {
        float g = sum > 0 ? rsqrtf((float)sum) : 0.f;
        (sd ? g1o : g0o)[grow] = g;
      }
    }
#pragma unroll
    for (int u = 0; u < 8; ++u) Ac[u] = An[u];
  }
}

// ---------------------------------------------------------- per-edge cosine
__global__ __launch_bounds__(256) void edge_kernel(const int* __restrict__ ei,
                                                   const uint32* __restrict__ Yq,
                                                   const float* __restrict__ g0,
                                                   const float* __restrict__ g1,
                                                   float* __restrict__ out) {
  int tid = blockIdx.x * blockDim.x + threadIdx.x;
  int g = tid >> 3, ls = tid & 7;
  int ng = (gridDim.x * blockDim.x) >> 3;
  for (int e = g; e < N_EDGES; e += ng) {
    int i = ei[e], j = ei[N_EDGES + e];
    uint4 a = *(const uint4*)(Yq + (size_t)i * 64 + ls * 4);
    uint4 b = *(const uint4*)(Yq + (size_t)j * 64 + 32 + ls * 4);
    int d = 0;
    d = SDOT4(a.x, b.x, d);
    d = SDOT4(a.y, b.y, d);
    d = SDOT4(a.z, b.z, d);
    d = SDOT4(a.w, b.w, d);
    d += __shfl_xor(d, 1);
    d += __shfl_xor(d, 2);
    d += __shfl_xor(d, 4);
    if (ls == 0) {
      out[e] = fmaf((float)d * g0[i] * g1[j], 0.5f, 0.5f);
    }
  }
}

// ------------------------------------------------------------------ launch
extern "C" void kernel_launch(void* const* d_in, const int* in_sizes, int n_in,
                              void* d_out, int out_size, void* d_ws, size_t ws_size,
                              hipStream_t stream) {
  const float* x = (const float*)d_in[0];
  const int* ei = (const int*)d_in[1];
  const float* W1 = (const float*)d_in[2];
  const float* b1 = (const float*)d_in[3];
  const float* gamma = (const float*)d_in[4];
  const float* beta = (const float*)d_in[5];
  const float* W2 = (const float*)d_in[6];
  const float* b2 = (const float*)d_in[7];
  float* out = (float*)d_out;

  auto align = [](size_t v) { return (v + 255) & ~(size_t)255; };
  char* ws = (char*)d_ws;
  size_t o_part = 0;
  size_t o_c0 = o_part + align((size_t)RANGES * BPR * RSIZE * sizeof(uint32));
  size_t o_c1 = o_c0 + align(N_NODES * sizeof(float));
  size_t o_sp = o_c1 + align(N_NODES * sizeof(float));
  size_t o_s2 = o_sp + align((size_t)ZGRID * 512 * sizeof(float));
  size_t o_q = o_s2 + align((size_t)FB * 512 * sizeof(float));
  size_t o_wct = o_q + align(C2 * sizeof(float));
  size_t o_g0 = o_wct + align((size_t)C2 * HID * sizeof(unsigned short));
  size_t o_g1 = o_g0 + align(N_NODES * sizeof(float));
  size_t o_Z = o_g1 + align(N_NODES * sizeof(float));
  size_t o_Y = o_Z + align((size_t)ZT * 1024 * sizeof(uint4));

  uint32* Part = (uint32*)(ws + o_part);
  float* c0f = (float*)(ws + o_c0);
  float* c1f = (float*)(ws + o_c1);
  float* Sp = (float*)(ws + o_sp);
  float* S2 = (float*)(ws + o_s2);
  float* q = (float*)(ws + o_q);
  unsigned short* Wct = (unsigned short*)(ws + o_wct);
  float* g0 = (float*)(ws + o_g0);
  float* g1 = (float*)(ws + o_g1);
  uint4* Zfrag = (uint4*)(ws + o_Z);
  uint32* Yq = (uint32*)(ws + o_Y);

  hist_kernel<<<RANGES * BPR, 1024, 0, stream>>>(ei, Part);
  creduce_kernel<<<(N_NODES + 255) / 256, 256, 0, stream>>>(Part, c0f, c1f);
  zpass_kernel<<<ZGRID, 256, 0, stream>>>(x, W1, b1, c0f, c1f, Zfrag, Sp);
  finalize_a<<<FB, 512, 0, stream>>>(Sp, S2);
  finalize_b<<<1, 512, 0, stream>>>(S2, gamma, beta, W2, b2, q, Wct);
  ygemm_kernel<<<YGRID, 512, 0, stream>>>(Zfrag, Wct, q, Yq, g0, g1);
  edge_kernel<<<2048, 256, 0, stream>>>(ei, Yq, g0, g1, out);
}